// Round 1
// baseline (728.700 us; speedup 1.0000x reference)
//
#include <hip/hip_runtime.h>
#include <stdint.h>

#define BB 4
#define SEQ 2048
#define DIM 1024
#define NH 16
#define DH 64
#define MM (BB*SEQ)   // 8192

typedef __attribute__((ext_vector_type(8))) __bf16 bf16x8;
typedef __attribute__((ext_vector_type(4))) float floatx4;

__device__ __forceinline__ unsigned short f2bf(float f) {
    union { float f; unsigned u; } v; v.f = f;
    unsigned u = v.u;
    u += 0x7FFF + ((u >> 16) & 1);   // round-to-nearest-even
    return (unsigned short)(u >> 16);
}

__device__ __forceinline__ bf16x8 ldb8(const unsigned short* p) {
    return *(const bf16x8*)(const void*)p;
}

// ---------------- Phase 1: fused QKV projection GEMM ----------------
// Q[bh][n][d], K[bh][n][d], Vt[bh][d][n]  (bf16 in ws)
#define LDA 40   // row stride in ushorts for As/Bs (16B-aligned rows, bank-spread)

__global__ __launch_bounds__(256)
void qkv_gemm(const float* __restrict__ x,
              const float* __restrict__ Wq, const float* __restrict__ bq,
              const float* __restrict__ Wk, const float* __restrict__ bk,
              const float* __restrict__ Wv, const float* __restrict__ bv,
              unsigned short* __restrict__ ws) {
    __shared__ unsigned short As[128 * LDA];
    __shared__ unsigned short Bs[128 * LDA];

    const int m0 = blockIdx.x * 128;
    const int t  = blockIdx.y >> 3;           // 0=q,1=k,2=v
    const int c0 = (blockIdx.y & 7) * 128;    // col within matrix

    const float* W    = (t == 0) ? Wq : (t == 1) ? Wk : Wv;
    const float* bias = (t == 0) ? bq : (t == 1) ? bk : bv;
    unsigned short* dst = ws + (size_t)t * ((size_t)MM * DIM);

    const int tid  = threadIdx.x;
    const int lane = tid & 63;
    const int wave = tid >> 6;
    const int wr = wave >> 1, wc = wave & 1;
    const int g = lane >> 4, ln = lane & 15;

    floatx4 acc[4][4];
    #pragma unroll
    for (int i = 0; i < 4; i++)
        #pragma unroll
        for (int j = 0; j < 4; j++) acc[i][j] = (floatx4){0.f,0.f,0.f,0.f};

    const int ar  = tid >> 1;          // A stage: row 0..127
    const int ak  = (tid & 1) * 16;    // k half
    const int bkr = tid & 31;          // B stage: k row 0..31
    const int bc  = (tid >> 5) * 16;   // col segment

    for (int kk = 0; kk < DIM; kk += 32) {
        // ---- stage A tile: x[m0+ar][kk+ak .. +16] -> As[ar][ak..]
        {
            const float4* s4 = (const float4*)(x + (size_t)(m0 + ar) * DIM + kk + ak);
            float4 f0 = s4[0], f1 = s4[1], f2 = s4[2], f3 = s4[3];
            unsigned pk[8];
            pk[0] = f2bf(f0.x) | ((unsigned)f2bf(f0.y) << 16);
            pk[1] = f2bf(f0.z) | ((unsigned)f2bf(f0.w) << 16);
            pk[2] = f2bf(f1.x) | ((unsigned)f2bf(f1.y) << 16);
            pk[3] = f2bf(f1.z) | ((unsigned)f2bf(f1.w) << 16);
            pk[4] = f2bf(f2.x) | ((unsigned)f2bf(f2.y) << 16);
            pk[5] = f2bf(f2.z) | ((unsigned)f2bf(f2.w) << 16);
            pk[6] = f2bf(f3.x) | ((unsigned)f2bf(f3.y) << 16);
            pk[7] = f2bf(f3.z) | ((unsigned)f2bf(f3.w) << 16);
            uint4* d = (uint4*)&As[ar * LDA + ak];
            d[0] = make_uint4(pk[0], pk[1], pk[2], pk[3]);
            d[1] = make_uint4(pk[4], pk[5], pk[6], pk[7]);
        }
        // ---- stage B tile (transposed): W[kk+bkr][c0+bc .. +16] -> Bs[bc+j][bkr]
        {
            const float4* s4 = (const float4*)(W + (size_t)(kk + bkr) * DIM + c0 + bc);
            float4 f0 = s4[0], f1 = s4[1], f2 = s4[2], f3 = s4[3];
            float fv[16] = {f0.x,f0.y,f0.z,f0.w, f1.x,f1.y,f1.z,f1.w,
                            f2.x,f2.y,f2.z,f2.w, f3.x,f3.y,f3.z,f3.w};
            #pragma unroll
            for (int j = 0; j < 16; j++)
                Bs[(bc + j) * LDA + bkr] = f2bf(fv[j]);
        }
        __syncthreads();

        bf16x8 a[4], b[4];
        #pragma unroll
        for (int fr = 0; fr < 4; fr++)
            a[fr] = ldb8(&As[(wr*64 + fr*16 + ln) * LDA + g*8]);
        #pragma unroll
        for (int fc = 0; fc < 4; fc++)
            b[fc] = ldb8(&Bs[(wc*64 + fc*16 + ln) * LDA + g*8]);

        #pragma unroll
        for (int fr = 0; fr < 4; fr++)
            #pragma unroll
            for (int fc = 0; fc < 4; fc++)
                acc[fr][fc] = __builtin_amdgcn_mfma_f32_16x16x32_bf16(
                    a[fr], b[fc], acc[fr][fc], 0, 0, 0);
        __syncthreads();
    }

    // epilogue: +bias, bf16, scatter to head-major layouts
    #pragma unroll
    for (int fc = 0; fc < 4; fc++) {
        const int cc = c0 + wc*64 + fc*16 + ln;
        const float bias_v = bias[cc];
        const int h = cc >> 6, d = cc & 63;
        #pragma unroll
        for (int fr = 0; fr < 4; fr++) {
            #pragma unroll
            for (int rr = 0; rr < 4; rr++) {
                const int mrow = m0 + wr*64 + fr*16 + g*4 + rr;
                const int bidx = mrow >> 11, nn = mrow & 2047;
                const float val = acc[fr][fc][rr] + bias_v;
                size_t idx;
                if (t < 2) idx = ((size_t)(bidx*NH + h)*SEQ + nn)*DH + d;
                else       idx = ((size_t)(bidx*NH + h)*DH + d)*SEQ + nn;
                dst[idx] = f2bf(val);
            }
        }
    }
}

// ---------------- Phase 2: flash attention ----------------
// 1 block = 4 waves; wave w owns Q rows [qt*64 + w*16, +16) of one (b,h).
__global__ __launch_bounds__(256)
void attn(const unsigned short* __restrict__ ws, float* __restrict__ out) {
    const int qt = blockIdx.x;   // 0..31
    const int h  = blockIdx.y;   // 0..15
    const int b  = blockIdx.z;   // 0..3
    const int bh = b*NH + h;

    const unsigned short* Qw = ws;
    const unsigned short* Kw = ws + (size_t)MM * DIM;
    const unsigned short* Vt = ws + 2 * (size_t)MM * DIM;

    __shared__ unsigned short P[4][16 * 72];   // per-wave P buffer, stride 72 (144B)

    const int tid  = threadIdx.x;
    const int lane = tid & 63;
    const int w    = tid >> 6;
    const int g = lane >> 4, ln = lane & 15;

    // Q fragments (A operand): row = lane&15
    const int qrow = qt*64 + w*16 + ln;
    const unsigned short* qp = Qw + ((size_t)bh*SEQ + qrow)*DH + g*8;
    const bf16x8 aq0 = ldb8(qp);
    const bf16x8 aq1 = ldb8(qp + 32);

    floatx4 acc[4];
    #pragma unroll
    for (int i = 0; i < 4; i++) acc[i] = (floatx4){0.f,0.f,0.f,0.f};
    float mrun[4] = {-1e30f,-1e30f,-1e30f,-1e30f};
    float lrun[4] = {0.f,0.f,0.f,0.f};

    const float SCALE = 0.17533044059810204f * 1.02857f;  // placeholder; set below
    // real scale: (1/sqrt(64)) * log2(e) = 0.125 * 1.4426950408889634
    const float SC = 0.125f * 1.4426950408889634f;
    (void)SCALE;

    for (int kt = 0; kt < SEQ/64; kt++) {
        const int kb = kt * 64;

        // S = Q K^T  (scaled into log2 domain)
        floatx4 s[4];
        #pragma unroll
        for (int fn = 0; fn < 4; fn++) {
            const unsigned short* kp = Kw + ((size_t)bh*SEQ + kb + fn*16 + ln)*DH + g*8;
            bf16x8 bk0 = ldb8(kp);
            bf16x8 bk1 = ldb8(kp + 32);
            floatx4 z = (floatx4){0.f,0.f,0.f,0.f};
            z = __builtin_amdgcn_mfma_f32_16x16x32_bf16(aq0, bk0, z, 0, 0, 0);
            z = __builtin_amdgcn_mfma_f32_16x16x32_bf16(aq1, bk1, z, 0, 0, 0);
            s[fn] = z;
        }
        #pragma unroll
        for (int fn = 0; fn < 4; fn++)
            #pragma unroll
            for (int r = 0; r < 4; r++) s[fn][r] *= SC;

        // online softmax (rows live on lanes sharing g; reduce over ln)
        float mx[4];
        #pragma unroll
        for (int r = 0; r < 4; r++)
            mx[r] = fmaxf(fmaxf(s[0][r], s[1][r]), fmaxf(s[2][r], s[3][r]));
        #pragma unroll
        for (int msk = 1; msk < 16; msk <<= 1)
            #pragma unroll
            for (int r = 0; r < 4; r++)
                mx[r] = fmaxf(mx[r], __shfl_xor(mx[r], msk, 64));

        float alpha[4];
        #pragma unroll
        for (int r = 0; r < 4; r++) {
            float mnew = fmaxf(mrun[r], mx[r]);
            alpha[r] = exp2f(mrun[r] - mnew);
            mrun[r] = mnew;
        }

        float rs[4] = {0.f,0.f,0.f,0.f};
        unsigned short pb[4][4];
        #pragma unroll
        for (int fn = 0; fn < 4; fn++)
            #pragma unroll
            for (int r = 0; r < 4; r++) {
                float p = exp2f(s[fn][r] - mrun[r]);
                rs[r] += p;
                pb[fn][r] = f2bf(p);
            }
        #pragma unroll
        for (int msk = 1; msk < 16; msk <<= 1)
            #pragma unroll
            for (int r = 0; r < 4; r++)
                rs[r] += __shfl_xor(rs[r], msk, 64);
        #pragma unroll
        for (int r = 0; r < 4; r++) lrun[r] = lrun[r]*alpha[r] + rs[r];
        #pragma unroll
        for (int fd = 0; fd < 4; fd++)
            #pragma unroll
            for (int r = 0; r < 4; r++) acc[fd][r] *= alpha[r];

        // P (C-layout) -> LDS -> A-layout
        #pragma unroll
        for (int fn = 0; fn < 4; fn++)
            #pragma unroll
            for (int r = 0; r < 4; r++)
                P[w][(g*4 + r)*72 + fn*16 + ln] = pb[fn][r];
        __syncthreads();   // ensures lgkmcnt drain before fragment reads

        bf16x8 ap0 = ldb8(&P[w][ln*72 + g*8]);
        bf16x8 ap1 = ldb8(&P[w][ln*72 + 32 + g*8]);

        #pragma unroll
        for (int fd = 0; fd < 4; fd++) {
            const unsigned short* vp = Vt + ((size_t)bh*DH + fd*16 + ln)*SEQ + kb + g*8;
            bf16x8 bv0 = ldb8(vp);
            bf16x8 bv1 = ldb8(vp + 32);
            acc[fd] = __builtin_amdgcn_mfma_f32_16x16x32_bf16(ap0, bv0, acc[fd], 0, 0, 0);
            acc[fd] = __builtin_amdgcn_mfma_f32_16x16x32_bf16(ap1, bv1, acc[fd], 0, 0, 0);
        }
        __syncthreads();   // WAR: protect P before next iteration's writes
    }

    // epilogue: out[b][n][h*64+d] = acc / l
    #pragma unroll
    for (int r = 0; r < 4; r++) {
        const float inv = 1.0f / lrun[r];
        const int n = qt*64 + w*16 + g*4 + r;
        #pragma unroll
        for (int fd = 0; fd < 4; fd++)
            out[((size_t)b*SEQ + n)*DIM + h*DH + fd*16 + ln] = acc[fd][r] * inv;
    }
}

extern "C" void kernel_launch(void* const* d_in, const int* in_sizes, int n_in,
                              void* d_out, int out_size, void* d_ws, size_t ws_size,
                              hipStream_t stream) {
    const float* x  = (const float*)d_in[0];
    const float* Wq = (const float*)d_in[1];
    const float* bq = (const float*)d_in[2];
    const float* Wk = (const float*)d_in[3];
    const float* bk = (const float*)d_in[4];
    const float* Wv = (const float*)d_in[5];
    const float* bv = (const float*)d_in[6];
    unsigned short* ws = (unsigned short*)d_ws;
    float* out = (float*)d_out;

    qkv_gemm<<<dim3(MM/128, 24), 256, 0, stream>>>(x, Wq, bq, Wk, bk, Wv, bv, ws);
    attn<<<dim3(SEQ/64, NH, BB), 256, 0, stream>>>(ws, out);
}

// Round 2
// 425.097 us; speedup vs baseline: 1.7142x; 1.7142x over previous
//
#include <hip/hip_runtime.h>
#include <stdint.h>

#define BB 4
#define SEQ 2048
#define DIM 1024
#define NH 16
#define DH 64
#define MM (BB*SEQ)   // 8192

typedef unsigned short u16;
typedef __attribute__((ext_vector_type(8))) __bf16 bf16x8;
typedef __attribute__((ext_vector_type(4))) float floatx4;
typedef __attribute__((ext_vector_type(4))) unsigned short u16x4;

__device__ __forceinline__ u16 f2bf(float f) {
    union { float f; unsigned u; } v; v.f = f;
    unsigned u = v.u;
    u += 0x7FFF + ((u >> 16) & 1);   // round-to-nearest-even
    return (u16)(u >> 16);
}

__device__ __forceinline__ bf16x8 ldb8(const u16* p) {
    return *(const bf16x8*)(const void*)p;
}

__device__ __forceinline__ void async_copy16(const u16* g, u16* l) {
    __builtin_amdgcn_global_load_lds(
        (const __attribute__((address_space(1))) unsigned int*)g,
        (__attribute__((address_space(3))) unsigned int*)l, 16, 0, 0);
}

// ---------------- prep: x fp32 -> bf16 ----------------
__global__ __launch_bounds__(256)
void conv_x(const float* __restrict__ x, u16* __restrict__ xb) {
    const size_t i = ((size_t)blockIdx.x * 256 + threadIdx.x) * 4;
    float4 f = *(const float4*)(x + i);
    u16x4 o = { f2bf(f.x), f2bf(f.y), f2bf(f.z), f2bf(f.w) };
    *(u16x4*)(xb + i) = o;
}

// ---------------- prep: W fp32 [k][n] -> Wt bf16 [n][k] ----------------
__global__ __launch_bounds__(256)
void conv_wt(const float* __restrict__ Wq, const float* __restrict__ Wk,
             const float* __restrict__ Wv, u16* __restrict__ Wt) {
    const int t = blockIdx.z;
    const float* W = (t == 0) ? Wq : (t == 1) ? Wk : Wv;
    u16* D = Wt + (size_t)t * DIM * DIM;
    __shared__ u16 T[64][65];
    const int k0 = blockIdx.x * 64, n0 = blockIdx.y * 64;
    const int tid = threadIdx.x;
    #pragma unroll
    for (int p = 0; p < 4; p++) {
        const int r = p * 16 + (tid >> 4), c = (tid & 15) * 4;
        float4 f = *(const float4*)(W + (size_t)(k0 + r) * DIM + n0 + c);
        T[c + 0][r] = f2bf(f.x); T[c + 1][r] = f2bf(f.y);
        T[c + 2][r] = f2bf(f.z); T[c + 3][r] = f2bf(f.w);
    }
    __syncthreads();
    #pragma unroll
    for (int p = 0; p < 4; p++) {
        const int rn = p * 16 + (tid >> 4), ck = (tid & 15) * 4;
        u16x4 v = { T[rn][ck], T[rn][ck + 1], T[rn][ck + 2], T[rn][ck + 3] };
        *(u16x4*)(D + (size_t)(n0 + rn) * DIM + k0 + ck) = v;
    }
}

// ---------------- Phase 1 (fast): bf16 GEMM, global_load_lds staging ----------------
// outputs: Q[bh][n][d], K[bh][n][d], Vt[bh][d][n]  (bf16)
__global__ __launch_bounds__(256)
void qkv_gemm2(const u16* __restrict__ xb, const u16* __restrict__ Wt,
               const float* __restrict__ bq, const float* __restrict__ bk,
               const float* __restrict__ bv, u16* __restrict__ ws) {
    __shared__ u16 As[128 * 32];
    __shared__ u16 Bs[128 * 32];

    const int m0 = blockIdx.x * 128;
    const int t  = blockIdx.y >> 3;
    const int c0 = (blockIdx.y & 7) * 128;
    const u16* Wtb = Wt + (size_t)t * DIM * DIM;
    const float* bias = (t == 0) ? bq : (t == 1) ? bk : bv;
    u16* dst = ws + (size_t)t * ((size_t)MM * DIM);

    const int tid  = threadIdx.x;
    const int lane = tid & 63;
    const int w    = tid >> 6;
    const int wr = w >> 1, wc = w & 1;
    const int g = lane >> 4, ln = lane & 15;

    floatx4 acc[4][4];
    #pragma unroll
    for (int i = 0; i < 4; i++)
        #pragma unroll
        for (int j = 0; j < 4; j++) acc[i][j] = (floatx4){0.f,0.f,0.f,0.f};

    // staging: lane l of wave w covers row (c*64 + w*16 + l/4), kseg (l&3)*8
    const int srow = w * 16 + (lane >> 2);
    const int skof = (lane & 3) * 8;

    for (int kk = 0; kk < DIM; kk += 32) {
        const u16* ga0 = xb  + (size_t)(m0 + srow)      * DIM + kk + skof;
        const u16* ga1 = xb  + (size_t)(m0 + 64 + srow) * DIM + kk + skof;
        const u16* gb0 = Wtb + (size_t)(c0 + srow)      * DIM + kk + skof;
        const u16* gb1 = Wtb + (size_t)(c0 + 64 + srow) * DIM + kk + skof;
        async_copy16(ga0, &As[w * 512]);
        async_copy16(ga1, &As[2048 + w * 512]);
        async_copy16(gb0, &Bs[w * 512]);
        async_copy16(gb1, &Bs[2048 + w * 512]);
        __syncthreads();

        bf16x8 a[4], b[4];
        #pragma unroll
        for (int fr = 0; fr < 4; fr++)
            a[fr] = ldb8(&As[(wr*64 + fr*16 + ln) * 32 + g*8]);
        #pragma unroll
        for (int fc = 0; fc < 4; fc++)
            b[fc] = ldb8(&Bs[(wc*64 + fc*16 + ln) * 32 + g*8]);

        #pragma unroll
        for (int fr = 0; fr < 4; fr++)
            #pragma unroll
            for (int fc = 0; fc < 4; fc++)
                acc[fr][fc] = __builtin_amdgcn_mfma_f32_16x16x32_bf16(
                    a[fr], b[fc], acc[fr][fc], 0, 0, 0);
        __syncthreads();
    }

    #pragma unroll
    for (int fc = 0; fc < 4; fc++) {
        const int cc = c0 + wc*64 + fc*16 + ln;
        const float bias_v = bias[cc];
        const int h = cc >> 6, d = cc & 63;
        #pragma unroll
        for (int fr = 0; fr < 4; fr++) {
            const int mrow = m0 + wr*64 + fr*16 + g*4;
            const int bidx = mrow >> 11, nn = mrow & 2047;
            if (t < 2) {
                #pragma unroll
                for (int rr = 0; rr < 4; rr++)
                    dst[((size_t)(bidx*NH + h)*SEQ + nn + rr)*DH + d] =
                        f2bf(acc[fr][fc][rr] + bias_v);
            } else {
                u16x4 v = { f2bf(acc[fr][fc][0] + bias_v), f2bf(acc[fr][fc][1] + bias_v),
                            f2bf(acc[fr][fc][2] + bias_v), f2bf(acc[fr][fc][3] + bias_v) };
                *(u16x4*)&dst[((size_t)(bidx*NH + h)*DH + d)*SEQ + nn] = v;
            }
        }
    }
}

// ---------------- Phase 1 (fallback, round-1 style, fp32 inputs) ----------------
#define LDA 40
__global__ __launch_bounds__(256)
void qkv_gemm(const float* __restrict__ x,
              const float* __restrict__ Wq, const float* __restrict__ bq,
              const float* __restrict__ Wk, const float* __restrict__ bk,
              const float* __restrict__ Wv, const float* __restrict__ bv,
              u16* __restrict__ ws) {
    __shared__ u16 As[128 * LDA];
    __shared__ u16 Bs[128 * LDA];
    const int m0 = blockIdx.x * 128;
    const int t  = blockIdx.y >> 3;
    const int c0 = (blockIdx.y & 7) * 128;
    const float* W    = (t == 0) ? Wq : (t == 1) ? Wk : Wv;
    const float* bias = (t == 0) ? bq : (t == 1) ? bk : bv;
    u16* dst = ws + (size_t)t * ((size_t)MM * DIM);
    const int tid  = threadIdx.x;
    const int lane = tid & 63;
    const int wave = tid >> 6;
    const int wr = wave >> 1, wc = wave & 1;
    const int g = lane >> 4, ln = lane & 15;
    floatx4 acc[4][4];
    #pragma unroll
    for (int i = 0; i < 4; i++)
        #pragma unroll
        for (int j = 0; j < 4; j++) acc[i][j] = (floatx4){0.f,0.f,0.f,0.f};
    const int ar  = tid >> 1;
    const int ak  = (tid & 1) * 16;
    const int bkr = tid & 31;
    const int bc  = (tid >> 5) * 16;
    for (int kk = 0; kk < DIM; kk += 32) {
        {
            const float4* s4 = (const float4*)(x + (size_t)(m0 + ar) * DIM + kk + ak);
            float4 f0 = s4[0], f1 = s4[1], f2 = s4[2], f3 = s4[3];
            unsigned pk[8];
            pk[0] = f2bf(f0.x) | ((unsigned)f2bf(f0.y) << 16);
            pk[1] = f2bf(f0.z) | ((unsigned)f2bf(f0.w) << 16);
            pk[2] = f2bf(f1.x) | ((unsigned)f2bf(f1.y) << 16);
            pk[3] = f2bf(f1.z) | ((unsigned)f2bf(f1.w) << 16);
            pk[4] = f2bf(f2.x) | ((unsigned)f2bf(f2.y) << 16);
            pk[5] = f2bf(f2.z) | ((unsigned)f2bf(f2.w) << 16);
            pk[6] = f2bf(f3.x) | ((unsigned)f2bf(f3.y) << 16);
            pk[7] = f2bf(f3.z) | ((unsigned)f2bf(f3.w) << 16);
            uint4* d = (uint4*)&As[ar * LDA + ak];
            d[0] = make_uint4(pk[0], pk[1], pk[2], pk[3]);
            d[1] = make_uint4(pk[4], pk[5], pk[6], pk[7]);
        }
        {
            const float4* s4 = (const float4*)(W + (size_t)(kk + bkr) * DIM + c0 + bc);
            float4 f0 = s4[0], f1 = s4[1], f2 = s4[2], f3 = s4[3];
            float fv[16] = {f0.x,f0.y,f0.z,f0.w, f1.x,f1.y,f1.z,f1.w,
                            f2.x,f2.y,f2.z,f2.w, f3.x,f3.y,f3.z,f3.w};
            #pragma unroll
            for (int j = 0; j < 16; j++)
                Bs[(bc + j) * LDA + bkr] = f2bf(fv[j]);
        }
        __syncthreads();
        bf16x8 a[4], b[4];
        #pragma unroll
        for (int fr = 0; fr < 4; fr++)
            a[fr] = ldb8(&As[(wr*64 + fr*16 + ln) * LDA + g*8]);
        #pragma unroll
        for (int fc = 0; fc < 4; fc++)
            b[fc] = ldb8(&Bs[(wc*64 + fc*16 + ln) * LDA + g*8]);
        #pragma unroll
        for (int fr = 0; fr < 4; fr++)
            #pragma unroll
            for (int fc = 0; fc < 4; fc++)
                acc[fr][fc] = __builtin_amdgcn_mfma_f32_16x16x32_bf16(
                    a[fr], b[fc], acc[fr][fc], 0, 0, 0);
        __syncthreads();
    }
    #pragma unroll
    for (int fc = 0; fc < 4; fc++) {
        const int cc = c0 + wc*64 + fc*16 + ln;
        const float bias_v = bias[cc];
        const int h = cc >> 6, d = cc & 63;
        #pragma unroll
        for (int fr = 0; fr < 4; fr++) {
            #pragma unroll
            for (int rr = 0; rr < 4; rr++) {
                const int mrow = m0 + wr*64 + fr*16 + g*4 + rr;
                const int bidx = mrow >> 11, nn = mrow & 2047;
                const float val = acc[fr][fc][rr] + bias_v;
                size_t idx;
                if (t < 2) idx = ((size_t)(bidx*NH + h)*SEQ + nn)*DH + d;
                else       idx = ((size_t)(bidx*NH + h)*DH + d)*SEQ + nn;
                dst[idx] = f2bf(val);
            }
        }
    }
}

// ---------------- Phase 2: flash attention, barrier-free, 32 rows/wave ----------------
__global__ __launch_bounds__(256)
void attn2(const u16* __restrict__ ws, float* __restrict__ out) {
    const int qt = blockIdx.x;   // 0..15
    const int h  = blockIdx.y;
    const int b  = blockIdx.z;
    const int bh = b*NH + h;

    const u16* Qw = ws;
    const u16* Kw = ws + (size_t)MM * DIM;
    const u16* Vt = ws + 2 * (size_t)MM * DIM;

    __shared__ u16 P[4][32 * 72];   // per-wave P buffer (32 rows x 64 keys, pad 8)

    const int tid  = threadIdx.x;
    const int lane = tid & 63;
    const int w    = tid >> 6;
    const int g = lane >> 4, ln = lane & 15;
    const int q0 = qt*128 + w*32;

    bf16x8 aq[2][2];
    #pragma unroll
    for (int rb = 0; rb < 2; rb++) {
        const u16* qp = Qw + ((size_t)bh*SEQ + q0 + rb*16 + ln)*DH + g*8;
        aq[rb][0] = ldb8(qp);
        aq[rb][1] = ldb8(qp + 32);
    }

    floatx4 acc[2][4];
    #pragma unroll
    for (int rb = 0; rb < 2; rb++)
        #pragma unroll
        for (int i = 0; i < 4; i++) acc[rb][i] = (floatx4){0.f,0.f,0.f,0.f};
    float lrun[2][4] = {{0.f,0.f,0.f,0.f},{0.f,0.f,0.f,0.f}};

    const float SC = 0.125f * 1.4426950408889634f;   // 1/sqrt(64) * log2(e)

    const u16* kbase = Kw + ((size_t)bh*SEQ + ln)*DH + g*8;
    const u16* vbase = Vt + ((size_t)bh*DH + ln)*SEQ + g*8;

    for (int kt = 0; kt < SEQ/64; kt++) {
        const int kb = kt * 64;

        // K fragments
        bf16x8 bk[4][2];
        #pragma unroll
        for (int fn = 0; fn < 4; fn++) {
            const u16* kp = kbase + (size_t)(kb + fn*16) * DH;
            bk[fn][0] = ldb8(kp);
            bk[fn][1] = ldb8(kp + 32);
        }

        // S = Q K^T
        floatx4 s[2][4];
        #pragma unroll
        for (int rb = 0; rb < 2; rb++)
            #pragma unroll
            for (int fn = 0; fn < 4; fn++) {
                floatx4 z = (floatx4){0.f,0.f,0.f,0.f};
                z = __builtin_amdgcn_mfma_f32_16x16x32_bf16(aq[rb][0], bk[fn][0], z, 0, 0, 0);
                z = __builtin_amdgcn_mfma_f32_16x16x32_bf16(aq[rb][1], bk[fn][1], z, 0, 0, 0);
                s[rb][fn] = z;
            }

        // p = exp2(s*SC); accumulate l per-lane; pack and store to per-wave LDS
        #pragma unroll
        for (int rb = 0; rb < 2; rb++)
            #pragma unroll
            for (int fn = 0; fn < 4; fn++)
                #pragma unroll
                for (int r = 0; r < 4; r++) {
                    float p = __builtin_amdgcn_exp2f(s[rb][fn][r] * SC);
                    lrun[rb][r] += p;
                    P[w][(rb*16 + g*4 + r)*72 + fn*16 + ln] = f2bf(p);
                }

        // read P^T as B-operand fragments (wave-internal; compiler inserts lgkmcnt wait)
        bf16x8 bp[2][2];
        #pragma unroll
        for (int rb = 0; rb < 2; rb++) {
            bp[rb][0] = ldb8(&P[w][(rb*16 + ln)*72 + g*8]);
            bp[rb][1] = ldb8(&P[w][(rb*16 + ln)*72 + 32 + g*8]);
        }

        // V^T fragments; acc^T += V^T P^T
        #pragma unroll
        for (int fd = 0; fd < 4; fd++) {
            const u16* vp = vbase + (size_t)(fd*16) * SEQ + kb;
            bf16x8 av0 = ldb8(vp);
            bf16x8 av1 = ldb8(vp + 32);
            #pragma unroll
            for (int rb = 0; rb < 2; rb++) {
                acc[rb][fd] = __builtin_amdgcn_mfma_f32_16x16x32_bf16(av0, bp[rb][0], acc[rb][fd], 0, 0, 0);
                acc[rb][fd] = __builtin_amdgcn_mfma_f32_16x16x32_bf16(av1, bp[rb][1], acc[rb][fd], 0, 0, 0);
            }
        }
    }

    // finalize l: reduce over the 16-lane group, then redistribute so lane ln holds row ln's sum
    #pragma unroll
    for (int rb = 0; rb < 2; rb++)
        #pragma unroll
        for (int r = 0; r < 4; r++) {
            float v = lrun[rb][r];
            v += __shfl_xor(v, 1, 64);
            v += __shfl_xor(v, 2, 64);
            v += __shfl_xor(v, 4, 64);
            v += __shfl_xor(v, 8, 64);
            lrun[rb][r] = v;
        }
    const int src = ((ln >> 2) << 4) | ln;   // a lane in group g = ln>>2
    #pragma unroll
    for (int rb = 0; rb < 2; rb++) {
        float t0 = __shfl(lrun[rb][0], src, 64);
        float t1 = __shfl(lrun[rb][1], src, 64);
        float t2 = __shfl(lrun[rb][2], src, 64);
        float t3 = __shfl(lrun[rb][3], src, 64);
        const int j = ln & 3;
        float l = (j < 2) ? ((j == 0) ? t0 : t1) : ((j == 2) ? t2 : t3);
        const float inv = 1.0f / l;
        const int n = q0 + rb*16 + ln;
        #pragma unroll
        for (int fd = 0; fd < 4; fd++) {
            floatx4 v = acc[rb][fd];
            float4 o = { v[0]*inv, v[1]*inv, v[2]*inv, v[3]*inv };
            *(float4*)&out[((size_t)b*SEQ + n)*DIM + h*DH + fd*16 + g*4] = o;
        }
    }
}

extern "C" void kernel_launch(void* const* d_in, const int* in_sizes, int n_in,
                              void* d_out, int out_size, void* d_ws, size_t ws_size,
                              hipStream_t stream) {
    const float* x  = (const float*)d_in[0];
    const float* Wq = (const float*)d_in[1];
    const float* bq = (const float*)d_in[2];
    const float* Wk = (const float*)d_in[3];
    const float* bk = (const float*)d_in[4];
    const float* Wv = (const float*)d_in[5];
    const float* bv = (const float*)d_in[6];
    u16* ws = (u16*)d_ws;
    float* out = (float*)d_out;

    const size_t need = (size_t)4 * MM * DIM * 2 + (size_t)3 * DIM * DIM * 2;
    if (ws_size >= need) {
        u16* xb = ws + (size_t)3 * MM * DIM;
        u16* Wt = ws + (size_t)4 * MM * DIM;
        conv_x<<<dim3(MM*DIM/1024), 256, 0, stream>>>(x, xb);
        conv_wt<<<dim3(DIM/64, DIM/64, 3), 256, 0, stream>>>(Wq, Wk, Wv, Wt);
        qkv_gemm2<<<dim3(MM/128, 24), 256, 0, stream>>>(xb, Wt, bq, bk, bv, ws);
    } else {
        qkv_gemm<<<dim3(MM/128, 24), 256, 0, stream>>>(x, Wq, bq, Wk, bk, Wv, bv, ws);
    }
    attn2<<<dim3(SEQ/128, NH, BB), 256, 0, stream>>>(ws, out);
}

// Round 3
// 406.140 us; speedup vs baseline: 1.7942x; 1.0467x over previous
//
#include <hip/hip_runtime.h>
#include <stdint.h>

#define BB 4
#define SEQ 2048
#define DIM 1024
#define NH 16
#define DH 64
#define MM (BB*SEQ)   // 8192

typedef unsigned short u16;
typedef __attribute__((ext_vector_type(8))) __bf16 bf16x8;
typedef __attribute__((ext_vector_type(4))) float floatx4;
typedef __attribute__((ext_vector_type(4))) unsigned short u16x4;

// 0.125 * log2(e): folded into Q at projection time
#define QSCALE 0.18033688011112042f

__device__ __forceinline__ u16 f2bf(float f) {
    union { float f; unsigned u; } v; v.f = f;
    unsigned u = v.u;
    u += 0x7FFF + ((u >> 16) & 1);   // RNE
    return (u16)(u >> 16);
}

__device__ __forceinline__ u16 f2bf_fast(float f) {   // round-half-up: <=0.5 ulp
    union { float f; unsigned u; } v; v.f = f;
    return (u16)((v.u + 0x8000u) >> 16);
}

__device__ __forceinline__ bf16x8 ldb8(const u16* p) {
    return *(const bf16x8*)(const void*)p;
}

__device__ __forceinline__ void async_copy16(const u16* g, u16* l) {
    __builtin_amdgcn_global_load_lds(
        (const __attribute__((address_space(1))) unsigned int*)g,
        (__attribute__((address_space(3))) unsigned int*)l, 16, 0, 0);
}

// ---------------- prep: x fp32 -> bf16 ----------------
__global__ __launch_bounds__(256)
void conv_x(const float* __restrict__ x, u16* __restrict__ xb) {
    const size_t i = ((size_t)blockIdx.x * 256 + threadIdx.x) * 4;
    float4 f = *(const float4*)(x + i);
    u16x4 o = { f2bf(f.x), f2bf(f.y), f2bf(f.z), f2bf(f.w) };
    *(u16x4*)(xb + i) = o;
}

// ---------------- prep: W fp32 [k][n] -> Wt bf16 [n][k] ----------------
__global__ __launch_bounds__(256)
void conv_wt(const float* __restrict__ Wq, const float* __restrict__ Wk,
             const float* __restrict__ Wv, u16* __restrict__ Wt) {
    const int t = blockIdx.z;
    const float* W = (t == 0) ? Wq : (t == 1) ? Wk : Wv;
    u16* D = Wt + (size_t)t * DIM * DIM;
    __shared__ u16 T[64][65];
    const int k0 = blockIdx.x * 64, n0 = blockIdx.y * 64;
    const int tid = threadIdx.x;
    #pragma unroll
    for (int p = 0; p < 4; p++) {
        const int r = p * 16 + (tid >> 4), c = (tid & 15) * 4;
        float4 f = *(const float4*)(W + (size_t)(k0 + r) * DIM + n0 + c);
        T[c + 0][r] = f2bf(f.x); T[c + 1][r] = f2bf(f.y);
        T[c + 2][r] = f2bf(f.z); T[c + 3][r] = f2bf(f.w);
    }
    __syncthreads();
    #pragma unroll
    for (int p = 0; p < 4; p++) {
        const int rn = p * 16 + (tid >> 4), ck = (tid & 15) * 4;
        u16x4 v = { T[rn][ck], T[rn][ck + 1], T[rn][ck + 2], T[rn][ck + 3] };
        *(u16x4*)(D + (size_t)(n0 + rn) * DIM + k0 + ck) = v;
    }
}

// ---------------- Phase 1 (fast): bf16 GEMM, global_load_lds staging ----------------
// outputs: Q[bh][n][d] (pre-scaled by QSCALE), K[bh][n][d], Vt[bh][d][n]
__global__ __launch_bounds__(256)
void qkv_gemm2(const u16* __restrict__ xb, const u16* __restrict__ Wt,
               const float* __restrict__ bq, const float* __restrict__ bk,
               const float* __restrict__ bv, u16* __restrict__ ws) {
    __shared__ u16 As[128 * 32];
    __shared__ u16 Bs[128 * 32];

    const int m0 = blockIdx.x * 128;
    const int t  = blockIdx.y >> 3;
    const int c0 = (blockIdx.y & 7) * 128;
    const u16* Wtb = Wt + (size_t)t * DIM * DIM;
    const float* bias = (t == 0) ? bq : (t == 1) ? bk : bv;
    const float osc = (t == 0) ? QSCALE : 1.0f;
    u16* dst = ws + (size_t)t * ((size_t)MM * DIM);

    const int tid  = threadIdx.x;
    const int lane = tid & 63;
    const int w    = tid >> 6;
    const int wr = w >> 1, wc = w & 1;
    const int g = lane >> 4, ln = lane & 15;

    floatx4 acc[4][4];
    #pragma unroll
    for (int i = 0; i < 4; i++)
        #pragma unroll
        for (int j = 0; j < 4; j++) acc[i][j] = (floatx4){0.f,0.f,0.f,0.f};

    const int srow = w * 16 + (lane >> 2);
    const int skof = (lane & 3) * 8;

    for (int kk = 0; kk < DIM; kk += 32) {
        const u16* ga0 = xb  + (size_t)(m0 + srow)      * DIM + kk + skof;
        const u16* ga1 = xb  + (size_t)(m0 + 64 + srow) * DIM + kk + skof;
        const u16* gb0 = Wtb + (size_t)(c0 + srow)      * DIM + kk + skof;
        const u16* gb1 = Wtb + (size_t)(c0 + 64 + srow) * DIM + kk + skof;
        async_copy16(ga0, &As[w * 512]);
        async_copy16(ga1, &As[2048 + w * 512]);
        async_copy16(gb0, &Bs[w * 512]);
        async_copy16(gb1, &Bs[2048 + w * 512]);
        __syncthreads();

        bf16x8 a[4], b[4];
        #pragma unroll
        for (int fr = 0; fr < 4; fr++)
            a[fr] = ldb8(&As[(wr*64 + fr*16 + ln) * 32 + g*8]);
        #pragma unroll
        for (int fc = 0; fc < 4; fc++)
            b[fc] = ldb8(&Bs[(wc*64 + fc*16 + ln) * 32 + g*8]);

        #pragma unroll
        for (int fr = 0; fr < 4; fr++)
            #pragma unroll
            for (int fc = 0; fc < 4; fc++)
                acc[fr][fc] = __builtin_amdgcn_mfma_f32_16x16x32_bf16(
                    a[fr], b[fc], acc[fr][fc], 0, 0, 0);
        __syncthreads();
    }

    #pragma unroll
    for (int fc = 0; fc < 4; fc++) {
        const int cc = c0 + wc*64 + fc*16 + ln;
        const float bias_v = bias[cc];
        const int h = cc >> 6, d = cc & 63;
        #pragma unroll
        for (int fr = 0; fr < 4; fr++) {
            const int mrow = m0 + wr*64 + fr*16 + g*4;
            const int bidx = mrow >> 11, nn = mrow & 2047;
            if (t < 2) {
                #pragma unroll
                for (int rr = 0; rr < 4; rr++)
                    dst[((size_t)(bidx*NH + h)*SEQ + nn + rr)*DH + d] =
                        f2bf((acc[fr][fc][rr] + bias_v) * osc);
            } else {
                u16x4 v = { f2bf(acc[fr][fc][0] + bias_v), f2bf(acc[fr][fc][1] + bias_v),
                            f2bf(acc[fr][fc][2] + bias_v), f2bf(acc[fr][fc][3] + bias_v) };
                *(u16x4*)&dst[((size_t)(bidx*NH + h)*DH + d)*SEQ + nn] = v;
            }
        }
    }
}

// ---------------- Phase 1 (fallback, fp32 inputs) ----------------
#define LDA 40
__global__ __launch_bounds__(256)
void qkv_gemm(const float* __restrict__ x,
              const float* __restrict__ Wq, const float* __restrict__ bq,
              const float* __restrict__ Wk, const float* __restrict__ bk,
              const float* __restrict__ Wv, const float* __restrict__ bv,
              u16* __restrict__ ws) {
    __shared__ u16 As[128 * LDA];
    __shared__ u16 Bs[128 * LDA];
    const int m0 = blockIdx.x * 128;
    const int t  = blockIdx.y >> 3;
    const int c0 = (blockIdx.y & 7) * 128;
    const float* W    = (t == 0) ? Wq : (t == 1) ? Wk : Wv;
    const float* bias = (t == 0) ? bq : (t == 1) ? bk : bv;
    const float osc = (t == 0) ? QSCALE : 1.0f;
    u16* dst = ws + (size_t)t * ((size_t)MM * DIM);
    const int tid  = threadIdx.x;
    const int lane = tid & 63;
    const int wave = tid >> 6;
    const int wr = wave >> 1, wc = wave & 1;
    const int g = lane >> 4, ln = lane & 15;
    floatx4 acc[4][4];
    #pragma unroll
    for (int i = 0; i < 4; i++)
        #pragma unroll
        for (int j = 0; j < 4; j++) acc[i][j] = (floatx4){0.f,0.f,0.f,0.f};
    const int ar  = tid >> 1;
    const int ak  = (tid & 1) * 16;
    const int bkr = tid & 31;
    const int bc  = (tid >> 5) * 16;
    for (int kk = 0; kk < DIM; kk += 32) {
        {
            const float4* s4 = (const float4*)(x + (size_t)(m0 + ar) * DIM + kk + ak);
            float4 f0 = s4[0], f1 = s4[1], f2 = s4[2], f3 = s4[3];
            unsigned pk[8];
            pk[0] = f2bf(f0.x) | ((unsigned)f2bf(f0.y) << 16);
            pk[1] = f2bf(f0.z) | ((unsigned)f2bf(f0.w) << 16);
            pk[2] = f2bf(f1.x) | ((unsigned)f2bf(f1.y) << 16);
            pk[3] = f2bf(f1.z) | ((unsigned)f2bf(f1.w) << 16);
            pk[4] = f2bf(f2.x) | ((unsigned)f2bf(f2.y) << 16);
            pk[5] = f2bf(f2.z) | ((unsigned)f2bf(f2.w) << 16);
            pk[6] = f2bf(f3.x) | ((unsigned)f2bf(f3.y) << 16);
            pk[7] = f2bf(f3.z) | ((unsigned)f2bf(f3.w) << 16);
            uint4* d = (uint4*)&As[ar * LDA + ak];
            d[0] = make_uint4(pk[0], pk[1], pk[2], pk[3]);
            d[1] = make_uint4(pk[4], pk[5], pk[6], pk[7]);
        }
        {
            const float4* s4 = (const float4*)(W + (size_t)(kk + bkr) * DIM + c0 + bc);
            float4 f0 = s4[0], f1 = s4[1], f2 = s4[2], f3 = s4[3];
            float fv[16] = {f0.x,f0.y,f0.z,f0.w, f1.x,f1.y,f1.z,f1.w,
                            f2.x,f2.y,f2.z,f2.w, f3.x,f3.y,f3.z,f3.w};
            #pragma unroll
            for (int j = 0; j < 16; j++)
                Bs[(bc + j) * LDA + bkr] = f2bf(fv[j]);
        }
        __syncthreads();
        bf16x8 a[4], b[4];
        #pragma unroll
        for (int fr = 0; fr < 4; fr++)
            a[fr] = ldb8(&As[(wr*64 + fr*16 + ln) * LDA + g*8]);
        #pragma unroll
        for (int fc = 0; fc < 4; fc++)
            b[fc] = ldb8(&Bs[(wc*64 + fc*16 + ln) * LDA + g*8]);
        #pragma unroll
        for (int fr = 0; fr < 4; fr++)
            #pragma unroll
            for (int fc = 0; fc < 4; fc++)
                acc[fr][fc] = __builtin_amdgcn_mfma_f32_16x16x32_bf16(
                    a[fr], b[fc], acc[fr][fc], 0, 0, 0);
        __syncthreads();
    }
    #pragma unroll
    for (int fc = 0; fc < 4; fc++) {
        const int cc = c0 + wc*64 + fc*16 + ln;
        const float bias_v = bias[cc];
        const int h = cc >> 6, d = cc & 63;
        #pragma unroll
        for (int fr = 0; fr < 4; fr++) {
            #pragma unroll
            for (int rr = 0; rr < 4; rr++) {
                const int mrow = m0 + wr*64 + fr*16 + g*4 + rr;
                const int bidx = mrow >> 11, nn = mrow & 2047;
                const float val = (acc[fr][fc][rr] + bias_v) * osc;
                size_t idx;
                if (t < 2) idx = ((size_t)(bidx*NH + h)*SEQ + nn)*DH + d;
                else       idx = ((size_t)(bidx*NH + h)*DH + d)*SEQ + nn;
                dst[idx] = f2bf(val);
            }
        }
    }
}

// ---------------- Phase 2: flash attention, software-pipelined ----------------
// One K-tile step: consumes K frags in bkc, prefetches next tile into bkn.
__device__ __forceinline__ void attn_step(
    int kt, const u16* __restrict__ kbase, const u16* __restrict__ vbase,
    u16* __restrict__ Pw, const bf16x8 aq[2][2],
    bf16x8 bkc[4][2], bf16x8 bkn[4][2],
    floatx4 acc[2][4], float lrun[2][4], int g, int ln)
{
    const int kb  = kt * 64;
    const int kbn = ((kt + 1) & 31) * 64;

    // V loads for this tile — issued first, consumed ~600 cycles later
    bf16x8 av[4][2];
    #pragma unroll
    for (int fd = 0; fd < 4; fd++) {
        const u16* vp = vbase + (size_t)(fd*16) * SEQ + kb;
        av[fd][0] = ldb8(vp);
        av[fd][1] = ldb8(vp + 32);
    }
    // prefetch NEXT K tile — consumed one full iteration later
    #pragma unroll
    for (int fn = 0; fn < 4; fn++) {
        const u16* kp = kbase + (size_t)(kbn + fn*16) * DH;
        bkn[fn][0] = ldb8(kp);
        bkn[fn][1] = ldb8(kp + 32);
    }

    // S = Q K^T  (Q pre-scaled: S is already in log2 domain)
    floatx4 s[2][4];
    #pragma unroll
    for (int rb = 0; rb < 2; rb++)
        #pragma unroll
        for (int fn = 0; fn < 4; fn++) {
            floatx4 z = (floatx4){0.f,0.f,0.f,0.f};
            z = __builtin_amdgcn_mfma_f32_16x16x32_bf16(aq[rb][0], bkc[fn][0], z, 0, 0, 0);
            z = __builtin_amdgcn_mfma_f32_16x16x32_bf16(aq[rb][1], bkc[fn][1], z, 0, 0, 0);
            s[rb][fn] = z;
        }

    // p = exp2(s); per-lane l accumulate; pack to per-wave LDS (C->A transpose)
    #pragma unroll
    for (int rb = 0; rb < 2; rb++)
        #pragma unroll
        for (int fn = 0; fn < 4; fn++)
            #pragma unroll
            for (int r = 0; r < 4; r++) {
                float p = __builtin_amdgcn_exp2f(s[rb][fn][r]);
                lrun[rb][r] += p;
                Pw[(rb*16 + g*4 + r)*72 + fn*16 + ln] = f2bf_fast(p);
            }

    bf16x8 bp[2][2];
    #pragma unroll
    for (int rb = 0; rb < 2; rb++) {
        bp[rb][0] = ldb8(&Pw[(rb*16 + ln)*72 + g*8]);
        bp[rb][1] = ldb8(&Pw[(rb*16 + ln)*72 + 32 + g*8]);
    }

    // acc^T += V^T P^T
    #pragma unroll
    for (int fd = 0; fd < 4; fd++)
        #pragma unroll
        for (int rb = 0; rb < 2; rb++) {
            acc[rb][fd] = __builtin_amdgcn_mfma_f32_16x16x32_bf16(av[fd][0], bp[rb][0], acc[rb][fd], 0, 0, 0);
            acc[rb][fd] = __builtin_amdgcn_mfma_f32_16x16x32_bf16(av[fd][1], bp[rb][1], acc[rb][fd], 0, 0, 0);
        }
}

__global__ __launch_bounds__(256, 2)
void attn3(const u16* __restrict__ ws, float* __restrict__ out) {
    const int qt = blockIdx.x;   // 0..15
    const int h  = blockIdx.y;
    const int b  = blockIdx.z;
    const int bh = b*NH + h;

    const u16* Qw = ws;
    const u16* Kw = ws + (size_t)MM * DIM;
    const u16* Vt = ws + 2 * (size_t)MM * DIM;

    __shared__ u16 P[4][32 * 72];

    const int tid  = threadIdx.x;
    const int lane = tid & 63;
    const int w    = tid >> 6;
    const int g = lane >> 4, ln = lane & 15;
    const int q0 = qt*128 + w*32;

    bf16x8 aq[2][2];
    #pragma unroll
    for (int rb = 0; rb < 2; rb++) {
        const u16* qp = Qw + ((size_t)bh*SEQ + q0 + rb*16 + ln)*DH + g*8;
        aq[rb][0] = ldb8(qp);
        aq[rb][1] = ldb8(qp + 32);
    }

    floatx4 acc[2][4];
    #pragma unroll
    for (int rb = 0; rb < 2; rb++)
        #pragma unroll
        for (int i = 0; i < 4; i++) acc[rb][i] = (floatx4){0.f,0.f,0.f,0.f};
    float lrun[2][4] = {{0.f,0.f,0.f,0.f},{0.f,0.f,0.f,0.f}};

    const u16* kbase = Kw + ((size_t)bh*SEQ + ln)*DH + g*8;
    const u16* vbase = Vt + ((size_t)bh*DH + ln)*SEQ + g*8;
    u16* Pw = &P[w][0];

    // preload K tile 0
    bf16x8 bkA[4][2], bkB[4][2];
    #pragma unroll
    for (int fn = 0; fn < 4; fn++) {
        const u16* kp = kbase + (size_t)(fn*16) * DH;
        bkA[fn][0] = ldb8(kp);
        bkA[fn][1] = ldb8(kp + 32);
    }

    for (int kt = 0; kt < 32; kt += 2) {
        attn_step(kt,     kbase, vbase, Pw, aq, bkA, bkB, acc, lrun, g, ln);
        attn_step(kt + 1, kbase, vbase, Pw, aq, bkB, bkA, acc, lrun, g, ln);
    }

    // finalize l and write out
    #pragma unroll
    for (int rb = 0; rb < 2; rb++)
        #pragma unroll
        for (int r = 0; r < 4; r++) {
            float v = lrun[rb][r];
            v += __shfl_xor(v, 1, 64);
            v += __shfl_xor(v, 2, 64);
            v += __shfl_xor(v, 4, 64);
            v += __shfl_xor(v, 8, 64);
            lrun[rb][r] = v;
        }
    const int src = ((ln >> 2) << 4) | ln;
    #pragma unroll
    for (int rb = 0; rb < 2; rb++) {
        float t0 = __shfl(lrun[rb][0], src, 64);
        float t1 = __shfl(lrun[rb][1], src, 64);
        float t2 = __shfl(lrun[rb][2], src, 64);
        float t3 = __shfl(lrun[rb][3], src, 64);
        const int j = ln & 3;
        float l = (j < 2) ? ((j == 0) ? t0 : t1) : ((j == 2) ? t2 : t3);
        const float inv = 1.0f / l;
        const int n = q0 + rb*16 + ln;
        #pragma unroll
        for (int fd = 0; fd < 4; fd++) {
            floatx4 v = acc[rb][fd];
            float4 o = { v[0]*inv, v[1]*inv, v[2]*inv, v[3]*inv };
            *(float4*)&out[((size_t)b*SEQ + n)*DIM + h*DH + fd*16 + g*4] = o;
        }
    }
}

extern "C" void kernel_launch(void* const* d_in, const int* in_sizes, int n_in,
                              void* d_out, int out_size, void* d_ws, size_t ws_size,
                              hipStream_t stream) {
    const float* x  = (const float*)d_in[0];
    const float* Wq = (const float*)d_in[1];
    const float* bq = (const float*)d_in[2];
    const float* Wk = (const float*)d_in[3];
    const float* bk = (const float*)d_in[4];
    const float* Wv = (const float*)d_in[5];
    const float* bv = (const float*)d_in[6];
    u16* ws = (u16*)d_ws;
    float* out = (float*)d_out;

    const size_t need = (size_t)4 * MM * DIM * 2 + (size_t)3 * DIM * DIM * 2;
    if (ws_size >= need) {
        u16* xb = ws + (size_t)3 * MM * DIM;
        u16* Wt = ws + (size_t)4 * MM * DIM;
        conv_x<<<dim3(MM*DIM/1024), 256, 0, stream>>>(x, xb);
        conv_wt<<<dim3(DIM/64, DIM/64, 3), 256, 0, stream>>>(Wq, Wk, Wv, Wt);
        qkv_gemm2<<<dim3(MM/128, 24), 256, 0, stream>>>(xb, Wt, bq, bk, bv, ws);
    } else {
        qkv_gemm<<<dim3(MM/128, 24), 256, 0, stream>>>(x, Wq, bq, Wk, bk, Wv, bv, ws);
    }
    attn3<<<dim3(SEQ/128, NH, BB), 256, 0, stream>>>(ws, out);
}

// Round 4
// 275.590 us; speedup vs baseline: 2.6441x; 1.4737x over previous
//
#include <hip/hip_runtime.h>
#include <hip/hip_bf16.h>
#include <stdint.h>

#define BB 4
#define SEQ 2048
#define DIM 1024
#define NH 16
#define DH 64
#define MM (BB*SEQ)   // 8192

typedef unsigned short u16;
typedef __attribute__((ext_vector_type(8))) __bf16 bf16x8;
typedef __attribute__((ext_vector_type(4))) float floatx4;
typedef __attribute__((ext_vector_type(4))) unsigned short u16x4;

// 0.125 * log2(e): folded into Q at projection time
#define QSCALE 0.18033688011112042f

__device__ __forceinline__ u16 f2bf(float f) {
    union { float f; unsigned u; } v; v.f = f;
    unsigned u = v.u;
    u += 0x7FFF + ((u >> 16) & 1);   // RNE
    return (u16)(u >> 16);
}

__device__ __forceinline__ bf16x8 ldb8(const u16* p) {
    return *(const bf16x8*)(const void*)p;
}

__device__ __forceinline__ void async_copy16(const u16* g, u16* l) {
    __builtin_amdgcn_global_load_lds(
        (const __attribute__((address_space(1))) unsigned int*)g,
        (__attribute__((address_space(3))) unsigned int*)l, 16, 0, 0);
}

// ---------------- prep: x fp32 -> bf16 ----------------
__global__ __launch_bounds__(256)
void conv_x(const float* __restrict__ x, u16* __restrict__ xb) {
    const size_t i = ((size_t)blockIdx.x * 256 + threadIdx.x) * 4;
    float4 f = *(const float4*)(x + i);
    u16x4 o = { f2bf(f.x), f2bf(f.y), f2bf(f.z), f2bf(f.w) };
    *(u16x4*)(xb + i) = o;
}

// ---------------- prep: W fp32 [k][n] -> Wt bf16 [n][k] ----------------
__global__ __launch_bounds__(256)
void conv_wt(const float* __restrict__ Wq, const float* __restrict__ Wk,
             const float* __restrict__ Wv, u16* __restrict__ Wt) {
    const int t = blockIdx.z;
    const float* W = (t == 0) ? Wq : (t == 1) ? Wk : Wv;
    u16* D = Wt + (size_t)t * DIM * DIM;
    __shared__ u16 T[64][65];
    const int k0 = blockIdx.x * 64, n0 = blockIdx.y * 64;
    const int tid = threadIdx.x;
    #pragma unroll
    for (int p = 0; p < 4; p++) {
        const int r = p * 16 + (tid >> 4), c = (tid & 15) * 4;
        float4 f = *(const float4*)(W + (size_t)(k0 + r) * DIM + n0 + c);
        T[c + 0][r] = f2bf(f.x); T[c + 1][r] = f2bf(f.y);
        T[c + 2][r] = f2bf(f.z); T[c + 3][r] = f2bf(f.w);
    }
    __syncthreads();
    #pragma unroll
    for (int p = 0; p < 4; p++) {
        const int rn = p * 16 + (tid >> 4), ck = (tid & 15) * 4;
        u16x4 v = { T[rn][ck], T[rn][ck + 1], T[rn][ck + 2], T[rn][ck + 3] };
        *(u16x4*)(D + (size_t)(n0 + rn) * DIM + k0 + ck) = v;
    }
}

// ---------------- Phase 1: bf16 GEMM, global_load_lds staging ----------------
// outputs: Q[bh][n][d] (pre-scaled by QSCALE), K[bh][n][d], Vt[bh][d][n]
__global__ __launch_bounds__(256)
void qkv_gemm2(const u16* __restrict__ xb, const u16* __restrict__ Wt,
               const float* __restrict__ bq, const float* __restrict__ bk,
               const float* __restrict__ bv, u16* __restrict__ ws) {
    __shared__ u16 As[128 * 32];
    __shared__ u16 Bs[128 * 32];

    const int m0 = blockIdx.x * 128;
    const int t  = blockIdx.y >> 3;
    const int c0 = (blockIdx.y & 7) * 128;
    const u16* Wtb = Wt + (size_t)t * DIM * DIM;
    const float* bias = (t == 0) ? bq : (t == 1) ? bk : bv;
    const float osc = (t == 0) ? QSCALE : 1.0f;
    u16* dst = ws + (size_t)t * ((size_t)MM * DIM);

    const int tid  = threadIdx.x;
    const int lane = tid & 63;
    const int w    = tid >> 6;
    const int wr = w >> 1, wc = w & 1;
    const int g = lane >> 4, ln = lane & 15;

    floatx4 acc[4][4];
    #pragma unroll
    for (int i = 0; i < 4; i++)
        #pragma unroll
        for (int j = 0; j < 4; j++) acc[i][j] = (floatx4){0.f,0.f,0.f,0.f};

    const int srow = w * 16 + (lane >> 2);
    const int skof = (lane & 3) * 8;

    for (int kk = 0; kk < DIM; kk += 32) {
        const u16* ga0 = xb  + (size_t)(m0 + srow)      * DIM + kk + skof;
        const u16* ga1 = xb  + (size_t)(m0 + 64 + srow) * DIM + kk + skof;
        const u16* gb0 = Wtb + (size_t)(c0 + srow)      * DIM + kk + skof;
        const u16* gb1 = Wtb + (size_t)(c0 + 64 + srow) * DIM + kk + skof;
        async_copy16(ga0, &As[w * 512]);
        async_copy16(ga1, &As[2048 + w * 512]);
        async_copy16(gb0, &Bs[w * 512]);
        async_copy16(gb1, &Bs[2048 + w * 512]);
        __syncthreads();

        bf16x8 a[4], b[4];
        #pragma unroll
        for (int fr = 0; fr < 4; fr++)
            a[fr] = ldb8(&As[(wr*64 + fr*16 + ln) * 32 + g*8]);
        #pragma unroll
        for (int fc = 0; fc < 4; fc++)
            b[fc] = ldb8(&Bs[(wc*64 + fc*16 + ln) * 32 + g*8]);

        #pragma unroll
        for (int fr = 0; fr < 4; fr++)
            #pragma unroll
            for (int fc = 0; fc < 4; fc++)
                acc[fr][fc] = __builtin_amdgcn_mfma_f32_16x16x32_bf16(
                    a[fr], b[fc], acc[fr][fc], 0, 0, 0);
        __syncthreads();
    }

    #pragma unroll
    for (int fc = 0; fc < 4; fc++) {
        const int cc = c0 + wc*64 + fc*16 + ln;
        const float bias_v = bias[cc];
        const int h = cc >> 6, d = cc & 63;
        #pragma unroll
        for (int fr = 0; fr < 4; fr++) {
            const int mrow = m0 + wr*64 + fr*16 + g*4;
            const int bidx = mrow >> 11, nn = mrow & 2047;
            if (t < 2) {
                #pragma unroll
                for (int rr = 0; rr < 4; rr++)
                    dst[((size_t)(bidx*NH + h)*SEQ + nn + rr)*DH + d] =
                        f2bf((acc[fr][fc][rr] + bias_v) * osc);
            } else {
                u16x4 v = { f2bf(acc[fr][fc][0] + bias_v), f2bf(acc[fr][fc][1] + bias_v),
                            f2bf(acc[fr][fc][2] + bias_v), f2bf(acc[fr][fc][3] + bias_v) };
                *(u16x4*)&dst[((size_t)(bidx*NH + h)*DH + d)*SEQ + nn] = v;
            }
        }
    }
}

// ---------------- Phase 1 (fallback, fp32 inputs) ----------------
#define LDA 40
__global__ __launch_bounds__(256)
void qkv_gemm(const float* __restrict__ x,
              const float* __restrict__ Wq, const float* __restrict__ bq,
              const float* __restrict__ Wk, const float* __restrict__ bk,
              const float* __restrict__ Wv, const float* __restrict__ bv,
              u16* __restrict__ ws) {
    __shared__ u16 As[128 * LDA];
    __shared__ u16 Bs[128 * LDA];
    const int m0 = blockIdx.x * 128;
    const int t  = blockIdx.y >> 3;
    const int c0 = (blockIdx.y & 7) * 128;
    const float* W    = (t == 0) ? Wq : (t == 1) ? Wk : Wv;
    const float* bias = (t == 0) ? bq : (t == 1) ? bk : bv;
    const float osc = (t == 0) ? QSCALE : 1.0f;
    u16* dst = ws + (size_t)t * ((size_t)MM * DIM);
    const int tid  = threadIdx.x;
    const int lane = tid & 63;
    const int wave = tid >> 6;
    const int wr = wave >> 1, wc = wave & 1;
    const int g = lane >> 4, ln = lane & 15;
    floatx4 acc[4][4];
    #pragma unroll
    for (int i = 0; i < 4; i++)
        #pragma unroll
        for (int j = 0; j < 4; j++) acc[i][j] = (floatx4){0.f,0.f,0.f,0.f};
    const int ar  = tid >> 1;
    const int ak  = (tid & 1) * 16;
    const int bkr = tid & 31;
    const int bc  = (tid >> 5) * 16;
    for (int kk = 0; kk < DIM; kk += 32) {
        {
            const float4* s4 = (const float4*)(x + (size_t)(m0 + ar) * DIM + kk + ak);
            float4 f0 = s4[0], f1 = s4[1], f2 = s4[2], f3 = s4[3];
            unsigned pk[8];
            pk[0] = f2bf(f0.x) | ((unsigned)f2bf(f0.y) << 16);
            pk[1] = f2bf(f0.z) | ((unsigned)f2bf(f0.w) << 16);
            pk[2] = f2bf(f1.x) | ((unsigned)f2bf(f1.y) << 16);
            pk[3] = f2bf(f1.z) | ((unsigned)f2bf(f1.w) << 16);
            pk[4] = f2bf(f2.x) | ((unsigned)f2bf(f2.y) << 16);
            pk[5] = f2bf(f2.z) | ((unsigned)f2bf(f2.w) << 16);
            pk[6] = f2bf(f3.x) | ((unsigned)f2bf(f3.y) << 16);
            pk[7] = f2bf(f3.z) | ((unsigned)f2bf(f3.w) << 16);
            uint4* d = (uint4*)&As[ar * LDA + ak];
            d[0] = make_uint4(pk[0], pk[1], pk[2], pk[3]);
            d[1] = make_uint4(pk[4], pk[5], pk[6], pk[7]);
        }
        {
            const float4* s4 = (const float4*)(W + (size_t)(kk + bkr) * DIM + c0 + bc);
            float4 f0 = s4[0], f1 = s4[1], f2 = s4[2], f3 = s4[3];
            float fv[16] = {f0.x,f0.y,f0.z,f0.w, f1.x,f1.y,f1.z,f1.w,
                            f2.x,f2.y,f2.z,f2.w, f3.x,f3.y,f3.z,f3.w};
            #pragma unroll
            for (int j = 0; j < 16; j++)
                Bs[(bc + j) * LDA + bkr] = f2bf(fv[j]);
        }
        __syncthreads();
        bf16x8 a[4], b[4];
        #pragma unroll
        for (int fr = 0; fr < 4; fr++)
            a[fr] = ldb8(&As[(wr*64 + fr*16 + ln) * LDA + g*8]);
        #pragma unroll
        for (int fc = 0; fc < 4; fc++)
            b[fc] = ldb8(&Bs[(wc*64 + fc*16 + ln) * LDA + g*8]);
        #pragma unroll
        for (int fr = 0; fr < 4; fr++)
            #pragma unroll
            for (int fc = 0; fc < 4; fc++)
                acc[fr][fc] = __builtin_amdgcn_mfma_f32_16x16x32_bf16(
                    a[fr], b[fc], acc[fr][fc], 0, 0, 0);
        __syncthreads();
    }
    #pragma unroll
    for (int fc = 0; fc < 4; fc++) {
        const int cc = c0 + wc*64 + fc*16 + ln;
        const float bias_v = bias[cc];
        const int h = cc >> 6, d = cc & 63;
        #pragma unroll
        for (int fr = 0; fr < 4; fr++) {
            #pragma unroll
            for (int rr = 0; rr < 4; rr++) {
                const int mrow = m0 + wr*64 + fr*16 + g*4 + rr;
                const int bidx = mrow >> 11, nn = mrow & 2047;
                const float val = (acc[fr][fc][rr] + bias_v) * osc;
                size_t idx;
                if (t < 2) idx = ((size_t)(bidx*NH + h)*SEQ + nn)*DH + d;
                else       idx = ((size_t)(bidx*NH + h)*DH + d)*SEQ + nn;
                dst[idx] = f2bf(val);
            }
        }
    }
}

// ---------------- Phase 2: flash attention, LDS-staged K/V, dbuf ----------------
// Block = 4 waves, 128 Q rows, one bh. K/V tiles (64 keys) staged via
// global_load_lds with XOR segment swizzle; double-buffered; 1 barrier/iter.
#define LDP 72   // P row stride (u16): 144B rows -> 16B-aligned, 2-way banks

__global__ __launch_bounds__(256, 3)
void attn4(const u16* __restrict__ ws, float* __restrict__ out) {
    const int qt = blockIdx.x;   // 0..15
    const int h  = blockIdx.y;
    const int b  = blockIdx.z;
    const int bh = b*NH + h;

    const u16* Qw = ws;
    const u16* Kw = ws + (size_t)MM * DIM;
    const u16* Vt = ws + 2 * (size_t)MM * DIM;

    __shared__ u16 Kbuf[2][4096];      // 64 keys x 64 d, seg-swizzled
    __shared__ u16 Vbuf[2][4096];      // 64 d x 64 keys, seg-swizzled
    __shared__ u16 P[4][32 * LDP];

    const int tid  = threadIdx.x;
    const int lane = tid & 63;
    const int w    = tid >> 6;
    const int g = lane >> 4, ln = lane & 15;
    const int q0 = qt*128 + w*32;

    // staging geometry: thread covers rows w*8 + lane/8 (+32 for half 1),
    // fetches segment (lane&7)^((lane>>3)&7) so LDS lane-order = swizzled layout
    const int srow = w*8 + (lane >> 3);
    const int sseg = (lane & 7) ^ ((lane >> 3) & 7);
    const u16* kg = Kw + ((size_t)bh*SEQ + srow)*DH + sseg*8;
    const u16* vg = Vt + ((size_t)bh*DH + srow)*SEQ + sseg*8;

    // fragment-read swizzled segment offsets (row&7 == ln&7)
    const int fs0 = ((0*4 + g) ^ (ln & 7)) * 8;   // h=0 segment
    const int fs1 = ((1*4 + g) ^ (ln & 7)) * 8;   // h=1 segment

    // Q fragments (B-operand): lane holds Q[q0+rb*16+ln][g*8+j (+32)]
    bf16x8 aq[2][2];
    #pragma unroll
    for (int rb = 0; rb < 2; rb++) {
        const u16* qp = Qw + ((size_t)bh*SEQ + q0 + rb*16 + ln)*DH + g*8;
        aq[rb][0] = ldb8(qp);
        aq[rb][1] = ldb8(qp + 32);
    }

    floatx4 acc[2][4];
    #pragma unroll
    for (int rb = 0; rb < 2; rb++)
        #pragma unroll
        for (int i = 0; i < 4; i++) acc[rb][i] = (floatx4){0.f,0.f,0.f,0.f};
    float lrun[2] = {0.f, 0.f};

    u16* Pw = &P[w][0];

    // stage tile 0 into buf 0
    {
        async_copy16(kg,                  &Kbuf[0][w*512]);
        async_copy16(kg + (size_t)32*DH,  &Kbuf[0][2048 + w*512]);
        async_copy16(vg,                  &Vbuf[0][w*512]);
        async_copy16(vg + (size_t)32*SEQ, &Vbuf[0][2048 + w*512]);
    }
    __syncthreads();

    for (int kt = 0; kt < 32; kt++) {
        const int cur = kt & 1;
        // prefetch next tile into the other buffer (async; barrier drains it)
        if (kt < 31) {
            const int nxt = cur ^ 1;
            const size_t ko = (size_t)(kt + 1) * 64 * DH;
            const size_t vo = (size_t)(kt + 1) * 64;
            async_copy16(kg + ko,                  &Kbuf[nxt][w*512]);
            async_copy16(kg + ko + (size_t)32*DH,  &Kbuf[nxt][2048 + w*512]);
            async_copy16(vg + vo,                  &Vbuf[nxt][w*512]);
            async_copy16(vg + vo + (size_t)32*SEQ, &Vbuf[nxt][2048 + w*512]);
        }

        const u16* Kc = &Kbuf[cur][0];
        const u16* Vc = &Vbuf[cur][0];

        // K fragments (A-operand): row = key = fn*16+ln
        bf16x8 bkf[4][2];
        #pragma unroll
        for (int fn = 0; fn < 4; fn++) {
            bkf[fn][0] = ldb8(&Kc[(fn*16 + ln)*64 + fs0]);
            bkf[fn][1] = ldb8(&Kc[(fn*16 + ln)*64 + fs1]);
        }
        // V^T fragments (A-operand): row = d = fd*16+ln
        bf16x8 av[4][2];
        #pragma unroll
        for (int fd = 0; fd < 4; fd++) {
            av[fd][0] = ldb8(&Vc[(fd*16 + ln)*64 + fs0]);
            av[fd][1] = ldb8(&Vc[(fd*16 + ln)*64 + fs1]);
        }

        // S^T = K Q^T : D[m=key][n=q], lane holds q=ln, keys fn*16+g*4+r
        #pragma unroll
        for (int rb = 0; rb < 2; rb++) {
            #pragma unroll
            for (int fn = 0; fn < 4; fn++) {
                floatx4 z = (floatx4){0.f,0.f,0.f,0.f};
                z = __builtin_amdgcn_mfma_f32_16x16x32_bf16(bkf[fn][0], aq[rb][0], z, 0, 0, 0);
                z = __builtin_amdgcn_mfma_f32_16x16x32_bf16(bkf[fn][1], aq[rb][1], z, 0, 0, 0);
                // p = exp2(s) (Q pre-scaled); accumulate l; pack 4 -> b64 LDS write
                float p0 = __builtin_amdgcn_exp2f(z[0]);
                float p1 = __builtin_amdgcn_exp2f(z[1]);
                float p2 = __builtin_amdgcn_exp2f(z[2]);
                float p3 = __builtin_amdgcn_exp2f(z[3]);
                lrun[rb] += (p0 + p1) + (p2 + p3);
                __hip_bfloat162 lo = __float22bfloat162_rn(make_float2(p0, p1));
                __hip_bfloat162 hi = __float22bfloat162_rn(make_float2(p2, p3));
                union { __hip_bfloat162 v2[2]; u16x4 v4; } u;
                u.v2[0] = lo; u.v2[1] = hi;
                *(u16x4*)&Pw[(rb*16 + ln)*LDP + fn*16 + g*4] = u.v4;
            }
        }

        // P fragments (B-operand): lane holds q=rb*16+ln, keys g*8+j (+32)
        bf16x8 bp[2][2];
        #pragma unroll
        for (int rb = 0; rb < 2; rb++) {
            bp[rb][0] = ldb8(&Pw[(rb*16 + ln)*LDP + g*8]);
            bp[rb][1] = ldb8(&Pw[(rb*16 + ln)*LDP + 32 + g*8]);
        }

        // acc^T += V^T P^T
        #pragma unroll
        for (int fd = 0; fd < 4; fd++)
            #pragma unroll
            for (int rb = 0; rb < 2; rb++) {
                acc[rb][fd] = __builtin_amdgcn_mfma_f32_16x16x32_bf16(av[fd][0], bp[rb][0], acc[rb][fd], 0, 0, 0);
                acc[rb][fd] = __builtin_amdgcn_mfma_f32_16x16x32_bf16(av[fd][1], bp[rb][1], acc[rb][fd], 0, 0, 0);
            }

        __syncthreads();   // publishes next tile, protects cur for overwrite at kt+2
    }

    // finalize: l lives per-lane for q=ln; sum partials across g (lane bits 4,5)
    #pragma unroll
    for (int rb = 0; rb < 2; rb++) {
        float v = lrun[rb];
        v += __shfl_xor(v, 16, 64);
        v += __shfl_xor(v, 32, 64);
        lrun[rb] = v;
    }
    #pragma unroll
    for (int rb = 0; rb < 2; rb++) {
        const float inv = 1.0f / lrun[rb];
        const int n = q0 + rb*16 + ln;
        #pragma unroll
        for (int fd = 0; fd < 4; fd++) {
            floatx4 v = acc[rb][fd];
            float4 o = { v[0]*inv, v[1]*inv, v[2]*inv, v[3]*inv };
            *(float4*)&out[((size_t)b*SEQ + n)*DIM + h*DH + fd*16 + g*4] = o;
        }
    }
}

extern "C" void kernel_launch(void* const* d_in, const int* in_sizes, int n_in,
                              void* d_out, int out_size, void* d_ws, size_t ws_size,
                              hipStream_t stream) {
    const float* x  = (const float*)d_in[0];
    const float* Wq = (const float*)d_in[1];
    const float* bq = (const float*)d_in[2];
    const float* Wk = (const float*)d_in[3];
    const float* bk = (const float*)d_in[4];
    const float* Wv = (const float*)d_in[5];
    const float* bv = (const float*)d_in[6];
    u16* ws = (u16*)d_ws;
    float* out = (float*)d_out;

    const size_t need = (size_t)4 * MM * DIM * 2 + (size_t)3 * DIM * DIM * 2;
    if (ws_size >= need) {
        u16* xb = ws + (size_t)3 * MM * DIM;
        u16* Wt = ws + (size_t)4 * MM * DIM;
        conv_x<<<dim3(MM*DIM/1024), 256, 0, stream>>>(x, xb);
        conv_wt<<<dim3(DIM/64, DIM/64, 3), 256, 0, stream>>>(Wq, Wk, Wv, Wt);
        qkv_gemm2<<<dim3(MM/128, 24), 256, 0, stream>>>(xb, Wt, bq, bk, bv, ws);
    } else {
        qkv_gemm<<<dim3(MM/128, 24), 256, 0, stream>>>(x, Wq, bq, Wk, bk, Wv, bv, ws);
    }
    attn4<<<dim3(SEQ/128, NH, BB), 256, 0, stream>>>(ws, out);
}

// Round 5
// 259.375 us; speedup vs baseline: 2.8094x; 1.0625x over previous
//
#include <hip/hip_runtime.h>
#include <hip/hip_bf16.h>
#include <stdint.h>

#define BB 4
#define SEQ 2048
#define DIM 1024
#define NH 16
#define DH 64
#define MM (BB*SEQ)   // 8192

typedef unsigned short u16;
typedef __attribute__((ext_vector_type(8))) __bf16 bf16x8;
typedef __attribute__((ext_vector_type(4))) float floatx4;
typedef __attribute__((ext_vector_type(4))) unsigned short u16x4;

// 0.125 * log2(e): folded into Q at projection time
#define QSCALE 0.18033688011112042f

__device__ __forceinline__ u16 f2bf(float f) {
    union { float f; unsigned u; } v; v.f = f;
    unsigned u = v.u;
    u += 0x7FFF + ((u >> 16) & 1);   // RNE
    return (u16)(u >> 16);
}

__device__ __forceinline__ bf16x8 ldb8(const u16* p) {
    return *(const bf16x8*)(const void*)p;
}

__device__ __forceinline__ void async_copy16(const u16* g, u16* l) {
    __builtin_amdgcn_global_load_lds(
        (const __attribute__((address_space(1))) unsigned int*)g,
        (__attribute__((address_space(3))) unsigned int*)l, 16, 0, 0);
}

// ---------------- prep: x fp32 -> bf16 ----------------
__global__ __launch_bounds__(256)
void conv_x(const float* __restrict__ x, u16* __restrict__ xb) {
    const size_t i = ((size_t)blockIdx.x * 256 + threadIdx.x) * 4;
    float4 f = *(const float4*)(x + i);
    u16x4 o = { f2bf(f.x), f2bf(f.y), f2bf(f.z), f2bf(f.w) };
    *(u16x4*)(xb + i) = o;
}

// ---------------- prep: W fp32 [k][n] -> Wt bf16 [n][k] ----------------
__global__ __launch_bounds__(256)
void conv_wt(const float* __restrict__ Wq, const float* __restrict__ Wk,
             const float* __restrict__ Wv, u16* __restrict__ Wt) {
    const int t = blockIdx.z;
    const float* W = (t == 0) ? Wq : (t == 1) ? Wk : Wv;
    u16* D = Wt + (size_t)t * DIM * DIM;
    __shared__ u16 T[64][65];
    const int k0 = blockIdx.x * 64, n0 = blockIdx.y * 64;
    const int tid = threadIdx.x;
    #pragma unroll
    for (int p = 0; p < 4; p++) {
        const int r = p * 16 + (tid >> 4), c = (tid & 15) * 4;
        float4 f = *(const float4*)(W + (size_t)(k0 + r) * DIM + n0 + c);
        T[c + 0][r] = f2bf(f.x); T[c + 1][r] = f2bf(f.y);
        T[c + 2][r] = f2bf(f.z); T[c + 3][r] = f2bf(f.w);
    }
    __syncthreads();
    #pragma unroll
    for (int p = 0; p < 4; p++) {
        const int rn = p * 16 + (tid >> 4), ck = (tid & 15) * 4;
        u16x4 v = { T[rn][ck], T[rn][ck + 1], T[rn][ck + 2], T[rn][ck + 3] };
        *(u16x4*)(D + (size_t)(n0 + rn) * DIM + k0 + ck) = v;
    }
}

// ---------------- Phase 1: bf16 GEMM, global_load_lds staging ----------------
// outputs: Q[bh][n][d] (pre-scaled by QSCALE), K[bh][n][d], Vt[bh][d][n]
// For Q/K the MFMA operands are swapped so D[m=c][col=token]: each lane then
// holds 4 consecutive features of one token -> u16x4 stores (coalesced).
__global__ __launch_bounds__(256)
void qkv_gemm2(const u16* __restrict__ xb, const u16* __restrict__ Wt,
               const float* __restrict__ bq, const float* __restrict__ bk,
               const float* __restrict__ bv, u16* __restrict__ ws) {
    __shared__ u16 As[128 * 32];
    __shared__ u16 Bs[128 * 32];

    const int m0 = blockIdx.x * 128;
    const int t  = blockIdx.y >> 3;
    const int c0 = (blockIdx.y & 7) * 128;
    const u16* Wtb = Wt + (size_t)t * DIM * DIM;
    const float* bias = (t == 0) ? bq : (t == 1) ? bk : bv;
    const float osc = (t == 0) ? QSCALE : 1.0f;
    u16* dst = ws + (size_t)t * ((size_t)MM * DIM);

    const int tid  = threadIdx.x;
    const int lane = tid & 63;
    const int w    = tid >> 6;
    const int wr = w >> 1, wc = w & 1;
    const int g = lane >> 4, ln = lane & 15;

    floatx4 acc[4][4];
    #pragma unroll
    for (int i = 0; i < 4; i++)
        #pragma unroll
        for (int j = 0; j < 4; j++) acc[i][j] = (floatx4){0.f,0.f,0.f,0.f};

    const int srow = w * 16 + (lane >> 2);
    const int skof = (lane & 3) * 8;

    for (int kk = 0; kk < DIM; kk += 32) {
        const u16* ga0 = xb  + (size_t)(m0 + srow)      * DIM + kk + skof;
        const u16* ga1 = xb  + (size_t)(m0 + 64 + srow) * DIM + kk + skof;
        const u16* gb0 = Wtb + (size_t)(c0 + srow)      * DIM + kk + skof;
        const u16* gb1 = Wtb + (size_t)(c0 + 64 + srow) * DIM + kk + skof;
        async_copy16(ga0, &As[w * 512]);
        async_copy16(ga1, &As[2048 + w * 512]);
        async_copy16(gb0, &Bs[w * 512]);
        async_copy16(gb1, &Bs[2048 + w * 512]);
        __syncthreads();

        bf16x8 a[4], b[4];
        #pragma unroll
        for (int fr = 0; fr < 4; fr++)
            a[fr] = ldb8(&As[(wr*64 + fr*16 + ln) * 32 + g*8]);
        #pragma unroll
        for (int fc = 0; fc < 4; fc++)
            b[fc] = ldb8(&Bs[(wc*64 + fc*16 + ln) * 32 + g*8]);

        if (t < 2) {
            #pragma unroll
            for (int fr = 0; fr < 4; fr++)
                #pragma unroll
                for (int fc = 0; fc < 4; fc++)
                    acc[fr][fc] = __builtin_amdgcn_mfma_f32_16x16x32_bf16(
                        b[fc], a[fr], acc[fr][fc], 0, 0, 0);
        } else {
            #pragma unroll
            for (int fr = 0; fr < 4; fr++)
                #pragma unroll
                for (int fc = 0; fc < 4; fc++)
                    acc[fr][fc] = __builtin_amdgcn_mfma_f32_16x16x32_bf16(
                        a[fr], b[fc], acc[fr][fc], 0, 0, 0);
        }
        __syncthreads();
    }

    if (t < 2) {
        // D[m=c][col=token]: lane holds c = cc+ (0..3), token = tok
        #pragma unroll
        for (int fc = 0; fc < 4; fc++) {
            const int cc = c0 + wc*64 + fc*16 + g*4;
            const float4 b4 = *(const float4*)&bias[cc];
            const int h = cc >> 6, d = cc & 63;
            #pragma unroll
            for (int fr = 0; fr < 4; fr++) {
                const int tok = m0 + wr*64 + fr*16 + ln;
                const int bidx = tok >> 11, nn = tok & 2047;
                u16x4 v = { f2bf((acc[fr][fc][0] + b4.x) * osc),
                            f2bf((acc[fr][fc][1] + b4.y) * osc),
                            f2bf((acc[fr][fc][2] + b4.z) * osc),
                            f2bf((acc[fr][fc][3] + b4.w) * osc) };
                *(u16x4*)&dst[((size_t)(bidx*NH + h)*SEQ + nn)*DH + d] = v;
            }
        }
    } else {
        // V^T: D[m=token][col=c]: lane holds 4 consecutive tokens of one feature
        #pragma unroll
        for (int fc = 0; fc < 4; fc++) {
            const int cc = c0 + wc*64 + fc*16 + ln;
            const float bias_v = bias[cc];
            const int h = cc >> 6, d = cc & 63;
            #pragma unroll
            for (int fr = 0; fr < 4; fr++) {
                const int mrow = m0 + wr*64 + fr*16 + g*4;
                const int bidx = mrow >> 11, nn = mrow & 2047;
                u16x4 v = { f2bf(acc[fr][fc][0] + bias_v), f2bf(acc[fr][fc][1] + bias_v),
                            f2bf(acc[fr][fc][2] + bias_v), f2bf(acc[fr][fc][3] + bias_v) };
                *(u16x4*)&dst[((size_t)(bidx*NH + h)*DH + d)*SEQ + nn] = v;
            }
        }
    }
}

// ---------------- Phase 1 (fallback, fp32 inputs) ----------------
#define LDA 40
__global__ __launch_bounds__(256)
void qkv_gemm(const float* __restrict__ x,
              const float* __restrict__ Wq, const float* __restrict__ bq,
              const float* __restrict__ Wk, const float* __restrict__ bk,
              const float* __restrict__ Wv, const float* __restrict__ bv,
              u16* __restrict__ ws) {
    __shared__ u16 As[128 * LDA];
    __shared__ u16 Bs[128 * LDA];
    const int m0 = blockIdx.x * 128;
    const int t  = blockIdx.y >> 3;
    const int c0 = (blockIdx.y & 7) * 128;
    const float* W    = (t == 0) ? Wq : (t == 1) ? Wk : Wv;
    const float* bias = (t == 0) ? bq : (t == 1) ? bk : bv;
    const float osc = (t == 0) ? QSCALE : 1.0f;
    u16* dst = ws + (size_t)t * ((size_t)MM * DIM);
    const int tid  = threadIdx.x;
    const int lane = tid & 63;
    const int wave = tid >> 6;
    const int wr = wave >> 1, wc = wave & 1;
    const int g = lane >> 4, ln = lane & 15;
    floatx4 acc[4][4];
    #pragma unroll
    for (int i = 0; i < 4; i++)
        #pragma unroll
        for (int j = 0; j < 4; j++) acc[i][j] = (floatx4){0.f,0.f,0.f,0.f};
    const int ar  = tid >> 1;
    const int ak  = (tid & 1) * 16;
    const int bkr = tid & 31;
    const int bc  = (tid >> 5) * 16;
    for (int kk = 0; kk < DIM; kk += 32) {
        {
            const float4* s4 = (const float4*)(x + (size_t)(m0 + ar) * DIM + kk + ak);
            float4 f0 = s4[0], f1 = s4[1], f2 = s4[2], f3 = s4[3];
            unsigned pk[8];
            pk[0] = f2bf(f0.x) | ((unsigned)f2bf(f0.y) << 16);
            pk[1] = f2bf(f0.z) | ((unsigned)f2bf(f0.w) << 16);
            pk[2] = f2bf(f1.x) | ((unsigned)f2bf(f1.y) << 16);
            pk[3] = f2bf(f1.z) | ((unsigned)f2bf(f1.w) << 16);
            pk[4] = f2bf(f2.x) | ((unsigned)f2bf(f2.y) << 16);
            pk[5] = f2bf(f2.z) | ((unsigned)f2bf(f2.w) << 16);
            pk[6] = f2bf(f3.x) | ((unsigned)f2bf(f3.y) << 16);
            pk[7] = f2bf(f3.z) | ((unsigned)f2bf(f3.w) << 16);
            uint4* d = (uint4*)&As[ar * LDA + ak];
            d[0] = make_uint4(pk[0], pk[1], pk[2], pk[3]);
            d[1] = make_uint4(pk[4], pk[5], pk[6], pk[7]);
        }
        {
            const float4* s4 = (const float4*)(W + (size_t)(kk + bkr) * DIM + c0 + bc);
            float4 f0 = s4[0], f1 = s4[1], f2 = s4[2], f3 = s4[3];
            float fv[16] = {f0.x,f0.y,f0.z,f0.w, f1.x,f1.y,f1.z,f1.w,
                            f2.x,f2.y,f2.z,f2.w, f3.x,f3.y,f3.z,f3.w};
            #pragma unroll
            for (int j = 0; j < 16; j++)
                Bs[(bc + j) * LDA + bkr] = f2bf(fv[j]);
        }
        __syncthreads();
        bf16x8 a[4], b[4];
        #pragma unroll
        for (int fr = 0; fr < 4; fr++)
            a[fr] = ldb8(&As[(wr*64 + fr*16 + ln) * LDA + g*8]);
        #pragma unroll
        for (int fc = 0; fc < 4; fc++)
            b[fc] = ldb8(&Bs[(wc*64 + fc*16 + ln) * LDA + g*8]);
        #pragma unroll
        for (int fr = 0; fr < 4; fr++)
            #pragma unroll
            for (int fc = 0; fc < 4; fc++)
                acc[fr][fc] = __builtin_amdgcn_mfma_f32_16x16x32_bf16(
                    a[fr], b[fc], acc[fr][fc], 0, 0, 0);
        __syncthreads();
    }
    #pragma unroll
    for (int fc = 0; fc < 4; fc++) {
        const int cc = c0 + wc*64 + fc*16 + ln;
        const float bias_v = bias[cc];
        const int h = cc >> 6, d = cc & 63;
        #pragma unroll
        for (int fr = 0; fr < 4; fr++) {
            #pragma unroll
            for (int rr = 0; rr < 4; rr++) {
                const int mrow = m0 + wr*64 + fr*16 + g*4 + rr;
                const int bidx = mrow >> 11, nn = mrow & 2047;
                const float val = (acc[fr][fc][rr] + bias_v) * osc;
                size_t idx;
                if (t < 2) idx = ((size_t)(bidx*NH + h)*SEQ + nn)*DH + d;
                else       idx = ((size_t)(bidx*NH + h)*DH + d)*SEQ + nn;
                dst[idx] = f2bf(val);
            }
        }
    }
}

// ---------------- Phase 2: flash attention, 256 Q rows/block ----------------
// Block = 4 waves, 64 Q rows/wave, one bh. Grid = 512 blocks = exactly 2/CU.
// K/V tiles (64 keys) staged via global_load_lds + XOR seg swizzle, dbuf,
// 1 barrier/iter. 64 MFMA/wave/iter against the same staging cost as attn4.
#define LDP 72   // P row stride (u16)

__global__ __launch_bounds__(256, 2)
void attn5(const u16* __restrict__ ws, float* __restrict__ out) {
    const int qt = blockIdx.x;   // 0..7
    const int h  = blockIdx.y;
    const int b  = blockIdx.z;
    const int bh = b*NH + h;

    const u16* Qw = ws;
    const u16* Kw = ws + (size_t)MM * DIM;
    const u16* Vt = ws + 2 * (size_t)MM * DIM;

    __shared__ u16 Kbuf[2][4096];      // 64 keys x 64 d, seg-swizzled
    __shared__ u16 Vbuf[2][4096];      // 64 d x 64 keys, seg-swizzled
    __shared__ u16 P[4][64 * LDP];     // per-wave P (64 q x 64 keys)

    const int tid  = threadIdx.x;
    const int lane = tid & 63;
    const int w    = tid >> 6;
    const int g = lane >> 4, ln = lane & 15;
    const int q0 = qt*256 + w*64;

    const int srow = w*8 + (lane >> 3);
    const int sseg = (lane & 7) ^ ((lane >> 3) & 7);
    const u16* kg = Kw + ((size_t)bh*SEQ + srow)*DH + sseg*8;
    const u16* vg = Vt + ((size_t)bh*DH + srow)*SEQ + sseg*8;

    const int fs0 = ((0*4 + g) ^ (ln & 7)) * 8;
    const int fs1 = ((1*4 + g) ^ (ln & 7)) * 8;

    // Q fragments (B-operand): lane holds Q[q0+rb*16+ln][g*8+j (+32)]
    bf16x8 aq[4][2];
    #pragma unroll
    for (int rb = 0; rb < 4; rb++) {
        const u16* qp = Qw + ((size_t)bh*SEQ + q0 + rb*16 + ln)*DH + g*8;
        aq[rb][0] = ldb8(qp);
        aq[rb][1] = ldb8(qp + 32);
    }

    floatx4 acc[4][4];
    #pragma unroll
    for (int rb = 0; rb < 4; rb++)
        #pragma unroll
        for (int i = 0; i < 4; i++) acc[rb][i] = (floatx4){0.f,0.f,0.f,0.f};
    float lrun[4] = {0.f, 0.f, 0.f, 0.f};

    u16* Pw = &P[w][0];

    // stage tile 0 into buf 0
    async_copy16(kg,                  &Kbuf[0][w*512]);
    async_copy16(kg + (size_t)32*DH,  &Kbuf[0][2048 + w*512]);
    async_copy16(vg,                  &Vbuf[0][w*512]);
    async_copy16(vg + (size_t)32*SEQ, &Vbuf[0][2048 + w*512]);
    __syncthreads();

    for (int kt = 0; kt < 32; kt++) {
        const int cur = kt & 1;
        if (kt < 31) {
            const int nxt = cur ^ 1;
            const size_t ko = (size_t)(kt + 1) * 64 * DH;
            const size_t vo = (size_t)(kt + 1) * 64;
            async_copy16(kg + ko,                  &Kbuf[nxt][w*512]);
            async_copy16(kg + ko + (size_t)32*DH,  &Kbuf[nxt][2048 + w*512]);
            async_copy16(vg + vo,                  &Vbuf[nxt][w*512]);
            async_copy16(vg + vo + (size_t)32*SEQ, &Vbuf[nxt][2048 + w*512]);
        }

        const u16* Kc = &Kbuf[cur][0];
        const u16* Vc = &Vbuf[cur][0];

        // K fragments (A-operand): row = key = fn*16+ln
        bf16x8 bkf[4][2];
        #pragma unroll
        for (int fn = 0; fn < 4; fn++) {
            bkf[fn][0] = ldb8(&Kc[(fn*16 + ln)*64 + fs0]);
            bkf[fn][1] = ldb8(&Kc[(fn*16 + ln)*64 + fs1]);
        }

        // S^T = K Q^T ; p = exp2(s); pack to per-wave P (b64 writes)
        #pragma unroll
        for (int rb = 0; rb < 4; rb++) {
            #pragma unroll
            for (int fn = 0; fn < 4; fn++) {
                floatx4 z = (floatx4){0.f,0.f,0.f,0.f};
                z = __builtin_amdgcn_mfma_f32_16x16x32_bf16(bkf[fn][0], aq[rb][0], z, 0, 0, 0);
                z = __builtin_amdgcn_mfma_f32_16x16x32_bf16(bkf[fn][1], aq[rb][1], z, 0, 0, 0);
                float p0 = __builtin_amdgcn_exp2f(z[0]);
                float p1 = __builtin_amdgcn_exp2f(z[1]);
                float p2 = __builtin_amdgcn_exp2f(z[2]);
                float p3 = __builtin_amdgcn_exp2f(z[3]);
                lrun[rb] += (p0 + p1) + (p2 + p3);
                __hip_bfloat162 lo = __float22bfloat162_rn(make_float2(p0, p1));
                __hip_bfloat162 hi = __float22bfloat162_rn(make_float2(p2, p3));
                union { __hip_bfloat162 v2[2]; u16x4 v4; } u;
                u.v2[0] = lo; u.v2[1] = hi;
                *(u16x4*)&Pw[(rb*16 + ln)*LDP + fn*16 + g*4] = u.v4;
            }
        }

        // V^T fragments (A-operand): row = d = fd*16+ln
        bf16x8 av[4][2];
        #pragma unroll
        for (int fd = 0; fd < 4; fd++) {
            av[fd][0] = ldb8(&Vc[(fd*16 + ln)*64 + fs0]);
            av[fd][1] = ldb8(&Vc[(fd*16 + ln)*64 + fs1]);
        }
        // P fragments (B-operand)
        bf16x8 bp[4][2];
        #pragma unroll
        for (int rb = 0; rb < 4; rb++) {
            bp[rb][0] = ldb8(&Pw[(rb*16 + ln)*LDP + g*8]);
            bp[rb][1] = ldb8(&Pw[(rb*16 + ln)*LDP + 32 + g*8]);
        }

        // acc^T += V^T P^T
        #pragma unroll
        for (int fd = 0; fd < 4; fd++)
            #pragma unroll
            for (int rb = 0; rb < 4; rb++) {
                acc[rb][fd] = __builtin_amdgcn_mfma_f32_16x16x32_bf16(av[fd][0], bp[rb][0], acc[rb][fd], 0, 0, 0);
                acc[rb][fd] = __builtin_amdgcn_mfma_f32_16x16x32_bf16(av[fd][1], bp[rb][1], acc[rb][fd], 0, 0, 0);
            }

        __syncthreads();   // publishes next tile; protects cur + P
    }

    // finalize: l per-lane for q=ln, partial over g -> reduce lane bits 4,5
    #pragma unroll
    for (int rb = 0; rb < 4; rb++) {
        float v = lrun[rb];
        v += __shfl_xor(v, 16, 64);
        v += __shfl_xor(v, 32, 64);
        lrun[rb] = v;
    }
    #pragma unroll
    for (int rb = 0; rb < 4; rb++) {
        const float inv = 1.0f / lrun[rb];
        const int n = q0 + rb*16 + ln;
        #pragma unroll
        for (int fd = 0; fd < 4; fd++) {
            floatx4 v = acc[rb][fd];
            float4 o = { v[0]*inv, v[1]*inv, v[2]*inv, v[3]*inv };
            *(float4*)&out[((size_t)b*SEQ + n)*DIM + h*DH + fd*16 + g*4] = o;
        }
    }
}

extern "C" void kernel_launch(void* const* d_in, const int* in_sizes, int n_in,
                              void* d_out, int out_size, void* d_ws, size_t ws_size,
                              hipStream_t stream) {
    const float* x  = (const float*)d_in[0];
    const float* Wq = (const float*)d_in[1];
    const float* bq = (const float*)d_in[2];
    const float* Wk = (const float*)d_in[3];
    const float* bk = (const float*)d_in[4];
    const float* Wv = (const float*)d_in[5];
    const float* bv = (const float*)d_in[6];
    u16* ws = (u16*)d_ws;
    float* out = (float*)d_out;

    const size_t need = (size_t)4 * MM * DIM * 2 + (size_t)3 * DIM * DIM * 2;
    if (ws_size >= need) {
        u16* xb = ws + (size_t)3 * MM * DIM;
        u16* Wt = ws + (size_t)4 * MM * DIM;
        conv_x<<<dim3(MM*DIM/1024), 256, 0, stream>>>(x, xb);
        conv_wt<<<dim3(DIM/64, DIM/64, 3), 256, 0, stream>>>(Wq, Wk, Wv, Wt);
        qkv_gemm2<<<dim3(MM/128, 24), 256, 0, stream>>>(xb, Wt, bq, bk, bv, ws);
    } else {
        qkv_gemm<<<dim3(MM/128, 24), 256, 0, stream>>>(x, Wq, bq, Wk, bk, Wv, bv, ws);
    }
    attn5<<<dim3(SEQ/256, NH, BB), 256, 0, stream>>>(ws, out);
}

// Round 6
// 253.230 us; speedup vs baseline: 2.8776x; 1.0243x over previous
//
#include <hip/hip_runtime.h>
#include <hip/hip_bf16.h>
#include <stdint.h>

#define BB 4
#define SEQ 2048
#define DIM 1024
#define NH 16
#define DH 64
#define MM (BB*SEQ)   // 8192

typedef unsigned short u16;
typedef __attribute__((ext_vector_type(8))) __bf16 bf16x8;
typedef __attribute__((ext_vector_type(4))) float floatx4;
typedef __attribute__((ext_vector_type(4))) unsigned short u16x4;

// 0.125 * log2(e): folded into Q at projection time
#define QSCALE 0.18033688011112042f

__device__ __forceinline__ u16 f2bf(float f) {
    union { float f; unsigned u; } v; v.f = f;
    unsigned u = v.u;
    u += 0x7FFF + ((u >> 16) & 1);   // RNE
    return (u16)(u >> 16);
}

__device__ __forceinline__ bf16x8 ldb8(const u16* p) {
    return *(const bf16x8*)(const void*)p;
}

__device__ __forceinline__ void async_copy16(const u16* g, u16* l) {
    __builtin_amdgcn_global_load_lds(
        (const __attribute__((address_space(1))) unsigned int*)g,
        (__attribute__((address_space(3))) unsigned int*)l, 16, 0, 0);
}

// ---------------- prep (merged): x fp32->bf16 ; W fp32 [k][n] -> Wt bf16 [n][k]
__global__ __launch_bounds__(256)
void prep(const float* __restrict__ x, u16* __restrict__ xb,
          const float* __restrict__ Wq, const float* __restrict__ Wk,
          const float* __restrict__ Wv, u16* __restrict__ Wt) {
    const int bx = blockIdx.x;
    const int tid = threadIdx.x;
    if (bx < 8192) {
        const size_t i = ((size_t)bx * 256 + tid) * 4;
        float4 f = *(const float4*)(x + i);
        u16x4 o = { f2bf(f.x), f2bf(f.y), f2bf(f.z), f2bf(f.w) };
        *(u16x4*)(xb + i) = o;
        return;
    }
    const int idx = bx - 8192;          // 0..767 = 16 x 16 x 3
    const int t = idx >> 8;
    const int r2 = idx & 255;
    const int k0 = (r2 >> 4) * 64, n0 = (r2 & 15) * 64;
    const float* W = (t == 0) ? Wq : (t == 1) ? Wk : Wv;
    u16* D = Wt + (size_t)t * DIM * DIM;
    __shared__ u16 T[64][65];
    #pragma unroll
    for (int p = 0; p < 4; p++) {
        const int r = p * 16 + (tid >> 4), c = (tid & 15) * 4;
        float4 f = *(const float4*)(W + (size_t)(k0 + r) * DIM + n0 + c);
        T[c + 0][r] = f2bf(f.x); T[c + 1][r] = f2bf(f.y);
        T[c + 2][r] = f2bf(f.z); T[c + 3][r] = f2bf(f.w);
    }
    __syncthreads();
    #pragma unroll
    for (int p = 0; p < 4; p++) {
        const int rn = p * 16 + (tid >> 4), ck = (tid & 15) * 4;
        u16x4 v = { T[rn][ck], T[rn][ck + 1], T[rn][ck + 2], T[rn][ck + 3] };
        *(u16x4*)(D + (size_t)(n0 + rn) * DIM + k0 + ck) = v;
    }
}

// ---------------- Phase 1: bf16 GEMM, dbuf LDS staging, 1 barrier/iter ----------
// outputs: Q[bh][n][d] (pre-scaled), K[bh][n][d], Vt[bh][d][n]
// LDS tiles 128x32, 16B-unit XOR swizzle (unit ^= (row>>1)&3): fragment
// reads are 2-way bank-aliased (free) instead of 8-way.
__global__ __launch_bounds__(256, 3)
void qkv_gemm3(const u16* __restrict__ xb, const u16* __restrict__ Wt,
               const float* __restrict__ bq, const float* __restrict__ bk,
               const float* __restrict__ bv, u16* __restrict__ ws) {
    __shared__ u16 As[2][4096];
    __shared__ u16 Bs[2][4096];

    const int m0 = blockIdx.x * 128;
    const int t  = blockIdx.y >> 3;
    const int c0 = (blockIdx.y & 7) * 128;
    const u16* Wtb = Wt + (size_t)t * DIM * DIM;
    const float* bias = (t == 0) ? bq : (t == 1) ? bk : bv;
    const float osc = (t == 0) ? QSCALE : 1.0f;
    u16* dst = ws + (size_t)t * ((size_t)MM * DIM);

    const int tid  = threadIdx.x;
    const int lane = tid & 63;
    const int w    = tid >> 6;
    const int wr = w >> 1, wc = w & 1;
    const int g = lane >> 4, ln = lane & 15;

    floatx4 acc[4][4];
    #pragma unroll
    for (int i = 0; i < 4; i++)
        #pragma unroll
        for (int j = 0; j < 4; j++) acc[i][j] = (floatx4){0.f,0.f,0.f,0.f};

    // staging: lane covers row srow=w*16+(lane>>2); LDS unit position lane&3
    // holds global 16B segment (lane&3)^((srow>>1)&3)  [(srow>>1)&3==(lane>>3)&3]
    const int srow = w*16 + (lane >> 2);
    const int gseg = (lane & 3) ^ ((lane >> 3) & 3);
    const u16* gA = xb  + (size_t)(m0 + srow) * DIM + gseg*8;
    const u16* gB = Wtb + (size_t)(c0 + srow) * DIM + gseg*8;

    // stage tile 0 -> buf 0
    async_copy16(gA,                   &As[0][w*512]);
    async_copy16(gA + (size_t)64*DIM,  &As[0][2048 + w*512]);
    async_copy16(gB,                   &Bs[0][w*512]);
    async_copy16(gB + (size_t)64*DIM,  &Bs[0][2048 + w*512]);
    __syncthreads();

    const int xu = (ln >> 1) & 3;   // fragment-read swizzle term

    for (int it = 0; it < 32; it++) {
        const int cur = it & 1;
        if (it < 31) {
            const int nxt = cur ^ 1;
            const int kk = (it + 1) * 32;
            async_copy16(gA + kk,                  &As[nxt][w*512]);
            async_copy16(gA + kk + (size_t)64*DIM, &As[nxt][2048 + w*512]);
            async_copy16(gB + kk,                  &Bs[nxt][w*512]);
            async_copy16(gB + kk + (size_t)64*DIM, &Bs[nxt][2048 + w*512]);
        }

        bf16x8 a[4], b[4];
        #pragma unroll
        for (int fr = 0; fr < 4; fr++)
            a[fr] = ldb8(&As[cur][(wr*64 + fr*16 + ln)*32 + (g ^ xu)*8]);
        #pragma unroll
        for (int fc = 0; fc < 4; fc++)
            b[fc] = ldb8(&Bs[cur][(wc*64 + fc*16 + ln)*32 + (g ^ xu)*8]);

        if (t < 2) {
            #pragma unroll
            for (int fr = 0; fr < 4; fr++)
                #pragma unroll
                for (int fc = 0; fc < 4; fc++)
                    acc[fr][fc] = __builtin_amdgcn_mfma_f32_16x16x32_bf16(
                        b[fc], a[fr], acc[fr][fc], 0, 0, 0);
        } else {
            #pragma unroll
            for (int fr = 0; fr < 4; fr++)
                #pragma unroll
                for (int fc = 0; fc < 4; fc++)
                    acc[fr][fc] = __builtin_amdgcn_mfma_f32_16x16x32_bf16(
                        a[fr], b[fc], acc[fr][fc], 0, 0, 0);
        }
        __syncthreads();   // drains next-tile DMA + protects cur
    }

    if (t < 2) {
        // D[m=c][col=token]: lane holds 4 consecutive features of token ln
        #pragma unroll
        for (int fc = 0; fc < 4; fc++) {
            const int cc = c0 + wc*64 + fc*16 + g*4;
            const float4 b4 = *(const float4*)&bias[cc];
            const int h = cc >> 6, d = cc & 63;
            #pragma unroll
            for (int fr = 0; fr < 4; fr++) {
                const int tok = m0 + wr*64 + fr*16 + ln;
                const int bidx = tok >> 11, nn = tok & 2047;
                u16x4 v = { f2bf((acc[fr][fc][0] + b4.x) * osc),
                            f2bf((acc[fr][fc][1] + b4.y) * osc),
                            f2bf((acc[fr][fc][2] + b4.z) * osc),
                            f2bf((acc[fr][fc][3] + b4.w) * osc) };
                *(u16x4*)&dst[((size_t)(bidx*NH + h)*SEQ + nn)*DH + d] = v;
            }
        }
    } else {
        // V^T: lane holds 4 consecutive tokens of one feature
        #pragma unroll
        for (int fc = 0; fc < 4; fc++) {
            const int cc = c0 + wc*64 + fc*16 + ln;
            const float bias_v = bias[cc];
            const int h = cc >> 6, d = cc & 63;
            #pragma unroll
            for (int fr = 0; fr < 4; fr++) {
                const int mrow = m0 + wr*64 + fr*16 + g*4;
                const int bidx = mrow >> 11, nn = mrow & 2047;
                u16x4 v = { f2bf(acc[fr][fc][0] + bias_v), f2bf(acc[fr][fc][1] + bias_v),
                            f2bf(acc[fr][fc][2] + bias_v), f2bf(acc[fr][fc][3] + bias_v) };
                *(u16x4*)&dst[((size_t)(bidx*NH + h)*DH + d)*SEQ + nn] = v;
            }
        }
    }
}

// ---------------- Phase 1 (fallback, fp32 inputs, small ws) ----------------
#define LDA 40
__global__ __launch_bounds__(256)
void qkv_gemm(const float* __restrict__ x,
              const float* __restrict__ Wq, const float* __restrict__ bq,
              const float* __restrict__ Wk, const float* __restrict__ bk,
              const float* __restrict__ Wv, const float* __restrict__ bv,
              u16* __restrict__ ws) {
    __shared__ u16 As[128 * LDA];
    __shared__ u16 Bs[128 * LDA];
    const int m0 = blockIdx.x * 128;
    const int t  = blockIdx.y >> 3;
    const int c0 = (blockIdx.y & 7) * 128;
    const float* W    = (t == 0) ? Wq : (t == 1) ? Wk : Wv;
    const float* bias = (t == 0) ? bq : (t == 1) ? bk : bv;
    const float osc = (t == 0) ? QSCALE : 1.0f;
    u16* dst = ws + (size_t)t * ((size_t)MM * DIM);
    const int tid  = threadIdx.x;
    const int lane = tid & 63;
    const int wave = tid >> 6;
    const int wr = wave >> 1, wc = wave & 1;
    const int g = lane >> 4, ln = lane & 15;
    floatx4 acc[4][4];
    #pragma unroll
    for (int i = 0; i < 4; i++)
        #pragma unroll
        for (int j = 0; j < 4; j++) acc[i][j] = (floatx4){0.f,0.f,0.f,0.f};
    const int ar  = tid >> 1;
    const int ak  = (tid & 1) * 16;
    const int bkr = tid & 31;
    const int bc  = (tid >> 5) * 16;
    for (int kk = 0; kk < DIM; kk += 32) {
        {
            const float4* s4 = (const float4*)(x + (size_t)(m0 + ar) * DIM + kk + ak);
            float4 f0 = s4[0], f1 = s4[1], f2 = s4[2], f3 = s4[3];
            unsigned pk[8];
            pk[0] = f2bf(f0.x) | ((unsigned)f2bf(f0.y) << 16);
            pk[1] = f2bf(f0.z) | ((unsigned)f2bf(f0.w) << 16);
            pk[2] = f2bf(f1.x) | ((unsigned)f2bf(f1.y) << 16);
            pk[3] = f2bf(f1.z) | ((unsigned)f2bf(f1.w) << 16);
            pk[4] = f2bf(f2.x) | ((unsigned)f2bf(f2.y) << 16);
            pk[5] = f2bf(f2.z) | ((unsigned)f2bf(f2.w) << 16);
            pk[6] = f2bf(f3.x) | ((unsigned)f2bf(f3.y) << 16);
            pk[7] = f2bf(f3.z) | ((unsigned)f2bf(f3.w) << 16);
            uint4* d = (uint4*)&As[ar * LDA + ak];
            d[0] = make_uint4(pk[0], pk[1], pk[2], pk[3]);
            d[1] = make_uint4(pk[4], pk[5], pk[6], pk[7]);
        }
        {
            const float4* s4 = (const float4*)(W + (size_t)(kk + bkr) * DIM + c0 + bc);
            float4 f0 = s4[0], f1 = s4[1], f2 = s4[2], f3 = s4[3];
            float fv[16] = {f0.x,f0.y,f0.z,f0.w, f1.x,f1.y,f1.z,f1.w,
                            f2.x,f2.y,f2.z,f2.w, f3.x,f3.y,f3.z,f3.w};
            #pragma unroll
            for (int j = 0; j < 16; j++)
                Bs[(bc + j) * LDA + bkr] = f2bf(fv[j]);
        }
        __syncthreads();
        bf16x8 a[4], b[4];
        #pragma unroll
        for (int fr = 0; fr < 4; fr++)
            a[fr] = ldb8(&As[(wr*64 + fr*16 + ln) * LDA + g*8]);
        #pragma unroll
        for (int fc = 0; fc < 4; fc++)
            b[fc] = ldb8(&Bs[(wc*64 + fc*16 + ln) * LDA + g*8]);
        #pragma unroll
        for (int fr = 0; fr < 4; fr++)
            #pragma unroll
            for (int fc = 0; fc < 4; fc++)
                acc[fr][fc] = __builtin_amdgcn_mfma_f32_16x16x32_bf16(
                    a[fr], b[fc], acc[fr][fc], 0, 0, 0);
        __syncthreads();
    }
    #pragma unroll
    for (int fc = 0; fc < 4; fc++) {
        const int cc = c0 + wc*64 + fc*16 + ln;
        const float bias_v = bias[cc];
        const int h = cc >> 6, d = cc & 63;
        #pragma unroll
        for (int fr = 0; fr < 4; fr++) {
            #pragma unroll
            for (int rr = 0; rr < 4; rr++) {
                const int mrow = m0 + wr*64 + fr*16 + g*4 + rr;
                const int bidx = mrow >> 11, nn = mrow & 2047;
                const float val = (acc[fr][fc][rr] + bias_v) * osc;
                size_t idx;
                if (t < 2) idx = ((size_t)(bidx*NH + h)*SEQ + nn)*DH + d;
                else       idx = ((size_t)(bidx*NH + h)*DH + d)*SEQ + nn;
                dst[idx] = f2bf(val);
            }
        }
    }
}

// ---------------- Phase 2: flash attention, 256 Q rows/block ----------------
#define LDP 72   // P row stride (u16)

__global__ __launch_bounds__(256, 2)
void attn5(const u16* __restrict__ ws, float* __restrict__ out) {
    const int qt = blockIdx.x;   // 0..7
    const int h  = blockIdx.y;
    const int b  = blockIdx.z;
    const int bh = b*NH + h;

    const u16* Qw = ws;
    const u16* Kw = ws + (size_t)MM * DIM;
    const u16* Vt = ws + 2 * (size_t)MM * DIM;

    __shared__ u16 Kbuf[2][4096];
    __shared__ u16 Vbuf[2][4096];
    __shared__ u16 P[4][64 * LDP];

    const int tid  = threadIdx.x;
    const int lane = tid & 63;
    const int w    = tid >> 6;
    const int g = lane >> 4, ln = lane & 15;
    const int q0 = qt*256 + w*64;

    const int srow = w*8 + (lane >> 3);
    const int sseg = (lane & 7) ^ ((lane >> 3) & 7);
    const u16* kg = Kw + ((size_t)bh*SEQ + srow)*DH + sseg*8;
    const u16* vg = Vt + ((size_t)bh*DH + srow)*SEQ + sseg*8;

    const int fs0 = ((0*4 + g) ^ (ln & 7)) * 8;
    const int fs1 = ((1*4 + g) ^ (ln & 7)) * 8;

    bf16x8 aq[4][2];
    #pragma unroll
    for (int rb = 0; rb < 4; rb++) {
        const u16* qp = Qw + ((size_t)bh*SEQ + q0 + rb*16 + ln)*DH + g*8;
        aq[rb][0] = ldb8(qp);
        aq[rb][1] = ldb8(qp + 32);
    }

    floatx4 acc[4][4];
    #pragma unroll
    for (int rb = 0; rb < 4; rb++)
        #pragma unroll
        for (int i = 0; i < 4; i++) acc[rb][i] = (floatx4){0.f,0.f,0.f,0.f};
    float lrun[4] = {0.f, 0.f, 0.f, 0.f};

    u16* Pw = &P[w][0];

    async_copy16(kg,                  &Kbuf[0][w*512]);
    async_copy16(kg + (size_t)32*DH,  &Kbuf[0][2048 + w*512]);
    async_copy16(vg,                  &Vbuf[0][w*512]);
    async_copy16(vg + (size_t)32*SEQ, &Vbuf[0][2048 + w*512]);
    __syncthreads();

    for (int kt = 0; kt < 32; kt++) {
        const int cur = kt & 1;
        if (kt < 31) {
            const int nxt = cur ^ 1;
            const size_t ko = (size_t)(kt + 1) * 64 * DH;
            const size_t vo = (size_t)(kt + 1) * 64;
            async_copy16(kg + ko,                  &Kbuf[nxt][w*512]);
            async_copy16(kg + ko + (size_t)32*DH,  &Kbuf[nxt][2048 + w*512]);
            async_copy16(vg + vo,                  &Vbuf[nxt][w*512]);
            async_copy16(vg + vo + (size_t)32*SEQ, &Vbuf[nxt][2048 + w*512]);
        }

        const u16* Kc = &Kbuf[cur][0];
        const u16* Vc = &Vbuf[cur][0];

        bf16x8 bkf[4][2];
        #pragma unroll
        for (int fn = 0; fn < 4; fn++) {
            bkf[fn][0] = ldb8(&Kc[(fn*16 + ln)*64 + fs0]);
            bkf[fn][1] = ldb8(&Kc[(fn*16 + ln)*64 + fs1]);
        }

        #pragma unroll
        for (int rb = 0; rb < 4; rb++) {
            #pragma unroll
            for (int fn = 0; fn < 4; fn++) {
                floatx4 z = (floatx4){0.f,0.f,0.f,0.f};
                z = __builtin_amdgcn_mfma_f32_16x16x32_bf16(bkf[fn][0], aq[rb][0], z, 0, 0, 0);
                z = __builtin_amdgcn_mfma_f32_16x16x32_bf16(bkf[fn][1], aq[rb][1], z, 0, 0, 0);
                float p0 = __builtin_amdgcn_exp2f(z[0]);
                float p1 = __builtin_amdgcn_exp2f(z[1]);
                float p2 = __builtin_amdgcn_exp2f(z[2]);
                float p3 = __builtin_amdgcn_exp2f(z[3]);
                lrun[rb] += (p0 + p1) + (p2 + p3);
                __hip_bfloat162 lo = __float22bfloat162_rn(make_float2(p0, p1));
                __hip_bfloat162 hi = __float22bfloat162_rn(make_float2(p2, p3));
                union { __hip_bfloat162 v2[2]; u16x4 v4; } u;
                u.v2[0] = lo; u.v2[1] = hi;
                *(u16x4*)&Pw[(rb*16 + ln)*LDP + fn*16 + g*4] = u.v4;
            }
        }

        bf16x8 av[4][2];
        #pragma unroll
        for (int fd = 0; fd < 4; fd++) {
            av[fd][0] = ldb8(&Vc[(fd*16 + ln)*64 + fs0]);
            av[fd][1] = ldb8(&Vc[(fd*16 + ln)*64 + fs1]);
        }
        bf16x8 bp[4][2];
        #pragma unroll
        for (int rb = 0; rb < 4; rb++) {
            bp[rb][0] = ldb8(&Pw[(rb*16 + ln)*LDP + g*8]);
            bp[rb][1] = ldb8(&Pw[(rb*16 + ln)*LDP + 32 + g*8]);
        }

        #pragma unroll
        for (int fd = 0; fd < 4; fd++)
            #pragma unroll
            for (int rb = 0; rb < 4; rb++) {
                acc[rb][fd] = __builtin_amdgcn_mfma_f32_16x16x32_bf16(av[fd][0], bp[rb][0], acc[rb][fd], 0, 0, 0);
                acc[rb][fd] = __builtin_amdgcn_mfma_f32_16x16x32_bf16(av[fd][1], bp[rb][1], acc[rb][fd], 0, 0, 0);
            }

        __syncthreads();
    }

    #pragma unroll
    for (int rb = 0; rb < 4; rb++) {
        float v = lrun[rb];
        v += __shfl_xor(v, 16, 64);
        v += __shfl_xor(v, 32, 64);
        lrun[rb] = v;
    }
    #pragma unroll
    for (int rb = 0; rb < 4; rb++) {
        const float inv = 1.0f / lrun[rb];
        const int n = q0 + rb*16 + ln;
        #pragma unroll
        for (int fd = 0; fd < 4; fd++) {
            floatx4 v = acc[rb][fd];
            float4 o = { v[0]*inv, v[1]*inv, v[2]*inv, v[3]*inv };
            *(float4*)&out[((size_t)b*SEQ + n)*DIM + h*DH + fd*16 + g*4] = o;
        }
    }
}

extern "C" void kernel_launch(void* const* d_in, const int* in_sizes, int n_in,
                              void* d_out, int out_size, void* d_ws, size_t ws_size,
                              hipStream_t stream) {
    const float* x  = (const float*)d_in[0];
    const float* Wq = (const float*)d_in[1];
    const float* bq = (const float*)d_in[2];
    const float* Wk = (const float*)d_in[3];
    const float* bk = (const float*)d_in[4];
    const float* Wv = (const float*)d_in[5];
    const float* bv = (const float*)d_in[6];
    u16* ws = (u16*)d_ws;
    float* out = (float*)d_out;

    const size_t need = (size_t)4 * MM * DIM * 2 + (size_t)3 * DIM * DIM * 2;
    if (ws_size >= need) {
        u16* xb = ws + (size_t)3 * MM * DIM;
        u16* Wt = ws + (size_t)4 * MM * DIM;
        prep<<<dim3(8192 + 768), 256, 0, stream>>>(x, xb, Wq, Wk, Wv, Wt);
        qkv_gemm3<<<dim3(MM/128, 24), 256, 0, stream>>>(xb, Wt, bq, bk, bv, ws);
    } else {
        qkv_gemm<<<dim3(MM/128, 24), 256, 0, stream>>>(x, Wq, bq, Wk, bk, Wv, bv, ws);
    }
    attn5<<<dim3(SEQ/256, NH, BB), 256, 0, stream>>>(ws, out);
}